// Round 9
// baseline (514.665 us; speedup 1.0000x reference)
//
#include <hip/hip_runtime.h>
#include <hip/hip_bf16.h>
#include <hip/hip_fp16.h>

#define NN 50000
#define NP 50176              // NN padded to multiple of 256 (GEMM tiles, no bounds checks)
#define EE 800000
#define ET (EE + NN)          // 850000 edges incl self-loops
#define NB_SCAN ((NN + 255) / 256)   // 196

typedef __attribute__((ext_vector_type(8))) short bf16x8;
typedef __attribute__((ext_vector_type(4))) float f32x4;
typedef __attribute__((ext_vector_type(2))) float f32x2;
typedef __attribute__((ext_vector_type(4))) unsigned int u32x4;

static __device__ __forceinline__ float bf2f(__hip_bfloat16 x) { return __bfloat162float(x); }
static __device__ __forceinline__ ushort f2bu(float f) {
    union { __hip_bfloat16 b; ushort u; } c;
    c.b = __float2bfloat16(f);
    return c.u;
}
static __device__ __forceinline__ float u2f(ushort u) {
    union { ushort u; __hip_bfloat16 b; } c;
    c.u = u;
    return __bfloat162float(c.b);
}
// fp8 e4m3 HW conversion (gfx950). Encode+decode use the same HW format -> self-consistent.
static __device__ __forceinline__ unsigned char f2fp8(float v) {
    int p = __builtin_amdgcn_cvt_pk_fp8_f32(v, v, 0, false);
    return (unsigned char)(p & 0xff);
}
// decode 4 packed fp8 bytes -> two f32 pairs, packed-FMA (v_pk_fma_f32) into two f32x2 accumulators.
static __device__ __forceinline__ void fp8acc_pk(unsigned v, f32x2 w2, f32x2& a01, f32x2& a23) {
#if __has_builtin(__builtin_amdgcn_cvt_pk_f32_fp8)
    f32x2 f01 = __builtin_amdgcn_cvt_pk_f32_fp8((int)v, false);
    f32x2 f23 = __builtin_amdgcn_cvt_pk_f32_fp8((int)v, true);
#else
    f32x2 f01 = { __builtin_amdgcn_cvt_f32_fp8(v, 0), __builtin_amdgcn_cvt_f32_fp8(v, 1) };
    f32x2 f23 = { __builtin_amdgcn_cvt_f32_fp8(v, 2), __builtin_amdgcn_cvt_f32_fp8(v, 3) };
#endif
    asm("v_pk_fma_f32 %0, %1, %2, %0" : "+v"(a01) : "v"(f01), "v"(w2));
    asm("v_pk_fma_f32 %0, %1, %2, %0" : "+v"(a23) : "v"(f23), "v"(w2));
}
// async global->LDS DMA, 16B per lane; lds dest must be wave-uniform base
static __device__ __forceinline__ void gl2lds(const ushort* g, ushort* l) {
    __builtin_amdgcn_global_load_lds(
        (const __attribute__((address_space(1))) void*)g,
        (__attribute__((address_space(3))) void*)l,
        16, 0, 0);
}

// ---------------------------------------------------------------- fused prep + CSR count
#define PA1 (256 * 448)
#define PA2 (448 * 448)
#define PA3 (448 * 32)
#define PXQ (NN * 64)   // x quads (256 ch / 4)
#define PTOT (PA1 + PA2 + PA3 + PXQ)
#define PBLK ((PTOT + 255) / 256)
#define CBLK ((ET + 255) / 256)

__global__ void gat_prepcnt_kernel(const float* __restrict__ W1, const float* __restrict__ W2,
                                   const float* __restrict__ W3, const float* __restrict__ x,
                                   ushort* __restrict__ Wt1, ushort* __restrict__ Wt2,
                                   ushort* __restrict__ Wt3, ushort* __restrict__ xb,
                                   const int* __restrict__ ei, int* __restrict__ cnt) {
    int b = blockIdx.x;
    if (b >= PBLK) {
        int i = (b - PBLK) * 256 + threadIdx.x;
        if (i < ET) {
            int dst = (i < EE) ? ei[EE + i] : (i - EE);
            atomicAdd(&cnt[dst], 1);
        }
        return;
    }
    int i = b * 256 + threadIdx.x;
    if (i < PA1) {
        int k = i / 448, n = i - k * 448;
        Wt1[(size_t)n * 256 + k] = f2bu(W1[i]);
        return;
    }
    i -= PA1;
    if (i < PA2) {
        int k = i / 448, n = i - k * 448;
        Wt2[(size_t)n * 448 + k] = f2bu(W2[i]);
        return;
    }
    i -= PA2;
    if (i < PA3) {
        int k = i / 32, n = i - k * 32;
        Wt3[(size_t)n * 448 + k] = f2bu(W3[i]);
        return;
    }
    i -= PA3;
    if (i < PXQ) {
        float4 f = ((const float4*)x)[i];
        ushort u[4] = {f2bu(f.x), f2bu(f.y), f2bu(f.z), f2bu(f.w)};
        ((uint2*)xb)[i] = *(const uint2*)u;
    }
}

// ---------------------------------------------------------------- CSR scans + fill
__global__ void gat_scan1_kernel(const int* __restrict__ cnt, int* __restrict__ tmp,
                                 int* __restrict__ part) {
    __shared__ int sm[256];
    int tid = threadIdx.x;
    int i = blockIdx.x * 256 + tid;
    int v = (i < NN) ? cnt[i] : 0;
    sm[tid] = v;
    __syncthreads();
    for (int o = 1; o < 256; o <<= 1) {
        int t = (tid >= o) ? sm[tid - o] : 0;
        __syncthreads();
        sm[tid] += t;
        __syncthreads();
    }
    if (i < NN) tmp[i] = sm[tid];
    if (tid == 255) part[blockIdx.x] = sm[255];
}

__global__ void gat_scan2_kernel(int* __restrict__ part) {
    __shared__ int sm[256];
    int tid = threadIdx.x;
    int v = (tid < NB_SCAN) ? part[tid] : 0;
    sm[tid] = v;
    __syncthreads();
    for (int o = 1; o < 256; o <<= 1) {
        int t = (tid >= o) ? sm[tid - o] : 0;
        __syncthreads();
        sm[tid] += t;
        __syncthreads();
    }
    part[tid] = sm[tid];
}

__global__ void gat_scan3_kernel(const int* __restrict__ tmp, const int* __restrict__ part,
                                 int* __restrict__ row_ptr) {
    int i = blockIdx.x * 256 + threadIdx.x;
    int off = (blockIdx.x > 0) ? part[blockIdx.x - 1] : 0;
    if (i < NN) row_ptr[i + 1] = tmp[i] + off;
    if (i == 0) row_ptr[0] = 0;
}

__global__ void gat_fill_kernel(const int* __restrict__ ei, const int* __restrict__ row_ptr,
                                int* __restrict__ fillc, int* __restrict__ colA) {
    int i = blockIdx.x * blockDim.x + threadIdx.x;
    if (i >= ET) return;
    int s, d;
    if (i < EE) { s = ei[i]; d = ei[EE + i]; }
    else        { s = d = i - EE; }
    int pos = row_ptr[d] + atomicAdd(&fillc[d], 1);
    colA[pos] = s;
}

// ---------------------------------------------------------------- Fused-head GEMM (layers 1 & 2)
// One block = 64 rows x ALL 448 cols (7 heads x 64ch). Per K-step: stage one 64x32 A-tile +
// full 448x32 B-slab (B table 0.4MB, L2-resident), then 28 MFMA/wave on ONE A-fragment.
// Replaces 7 per-head blocks that each staged the same A-tile (7x A HBM/L2 traffic, 7x
// barriers, 7x staging). Accumulation order per head identical to the per-head kernel ->
// bitwise-identical as8/ad8/C. C written fp8. acc[7][4] = 112 VGPR.
__global__ __launch_bounds__(256) void gat_gemmF_kernel(
    const ushort* __restrict__ A, const ushort* __restrict__ Wt,
    unsigned char* __restrict__ C8,
    const float* __restrict__ Asrc, const float* __restrict__ Adst,
    float* __restrict__ as8, float* __restrict__ ad8,
    int K) {
    __shared__ __align__(16) ushort As[2][64 * 32];     // 8 KB
    __shared__ __align__(16) ushort Bs[2][448 * 32];    // 56 KB
    int tid = threadIdx.x;
    int wave = tid >> 6, lane = tid & 63;
    int lrow = lane & 15, lq = lane >> 4;
    int m0 = blockIdx.x * 64;
    int srow = lane >> 2, schunk = (lane & 3) * 8;      // 4 lanes per 64B row-chunk
    f32x4 acc[7][4] = {};

    int KT = K / 32;
    {
        const ushort* gp = A + (size_t)(m0 + wave * 16 + srow) * K + schunk;
        gl2lds(gp, &As[0][(wave * 16) * 32]);
#pragma unroll
        for (int q = 0; q < 7; q++) {
            const ushort* gb = Wt + (size_t)(wave * 112 + q * 16 + srow) * K + schunk;
            gl2lds(gb, &Bs[0][(wave * 112 + q * 16) * 32]);
        }
    }
    for (int kt = 0; kt < KT; kt++) {
        __syncthreads();
        if (kt + 1 < KT) {
            int nb = (kt + 1) & 1, k0 = (kt + 1) * 32;
            const ushort* gp = A + (size_t)(m0 + wave * 16 + srow) * K + k0 + schunk;
            gl2lds(gp, &As[nb][(wave * 16) * 32]);
#pragma unroll
            for (int q = 0; q < 7; q++) {
                const ushort* gb = Wt + (size_t)(wave * 112 + q * 16 + srow) * K + k0 + schunk;
                gl2lds(gb, &Bs[nb][(wave * 112 + q * 16) * 32]);
            }
        }
        int b = kt & 1;
        bf16x8 af = *(const bf16x8*)&As[b][(wave * 16 + lrow) * 32 + lq * 8];
#pragma unroll
        for (int h = 0; h < 7; h++)
#pragma unroll
            for (int ng = 0; ng < 4; ng++) {
                bf16x8 bf = *(const bf16x8*)&Bs[b][(h * 64 + ng * 16 + lrow) * 32 + lq * 8];
                acc[h][ng] = __builtin_amdgcn_mfma_f32_16x16x32_bf16(af, bf, acc[h][ng], 0, 0, 0);
            }
    }
    // C-write: fp8; C/D layout col=lane&15 within ng group, row=lq*4+r
#pragma unroll
    for (int h = 0; h < 7; h++)
#pragma unroll
        for (int ng = 0; ng < 4; ng++)
#pragma unroll
            for (int r = 0; r < 4; r++) {
                int row = m0 + wave * 16 + lq * 4 + r;
                int col = h * 64 + ng * 16 + lrow;
                if (row < NN)
                    C8[(size_t)row * 448 + col] = f2fp8(acc[h][ng][r]);
            }
    // fused alpha: per head, ps/pd partial over 4 ng, 16-lane shfl reduce (same order as before)
#pragma unroll
    for (int h = 0; h < 7; h++) {
        float as_l[4], ad_l[4];
#pragma unroll
        for (int ng = 0; ng < 4; ng++) {
            as_l[ng] = Asrc[h * 64 + ng * 16 + lrow];
            ad_l[ng] = Adst[h * 64 + ng * 16 + lrow];
        }
#pragma unroll
        for (int r = 0; r < 4; r++) {
            float ps = 0.f, pd = 0.f;
#pragma unroll
            for (int ng = 0; ng < 4; ng++) {
                ps += acc[h][ng][r] * as_l[ng];
                pd += acc[h][ng][r] * ad_l[ng];
            }
#pragma unroll
            for (int o = 1; o < 16; o <<= 1) {
                ps += __shfl_xor(ps, o);
                pd += __shfl_xor(pd, o);
            }
            int row = m0 + wave * 16 + lq * 4 + r;
            if (lrow == 0 && row < NN) {
                as8[(size_t)row * 8 + h] = ps;
                ad8[(size_t)row * 8 + h] = pd;
            }
        }
    }
}

// ---------------------------------------------------------------- GEMM core (layer 3 only: DOA=2, bf16 out)
#define GBN 64
#define GBK 32

template <int RF, int DOA, int OM>
__global__ __launch_bounds__(256) void gat_gemm_kernel(
    const ushort* __restrict__ A, const ushort* __restrict__ Wt,
    void* __restrict__ Cv,
    const float* __restrict__ Asrc, const float* __restrict__ Adst,
    float* __restrict__ as8, float* __restrict__ ad8,
    int M, int K, int N) {
    constexpr int GBM = RF * 64;
    __shared__ __align__(16) ushort As[2][GBM * GBK];
    __shared__ __align__(16) ushort Bs[2][GBN * GBK];
    int tid = threadIdx.x;
    int wave = tid >> 6, lane = tid & 63;
    int lrow = lane & 15, lq = lane >> 4;
    int mt = blockIdx.x, head = blockIdx.y;
    int m0 = mt * GBM, n0 = head * GBN;

    int srow = lane >> 2, schunk = (lane & 3) * 8;      // 4 lanes per 64B row-chunk
    f32x4 acc[RF][4] = {};

    int KT = K / GBK;
    {
#pragma unroll
        for (int q = 0; q < RF; q++) {
            const ushort* gp = A + (size_t)(m0 + wave * RF * 16 + q * 16 + srow) * K + schunk;
            gl2lds(gp, &As[0][(wave * RF * 16 + q * 16) * GBK]);
        }
        const ushort* gb = Wt + (size_t)(n0 + wave * 16 + srow) * K + schunk;
        gl2lds(gb, &Bs[0][wave * 16 * GBK]);
    }
    for (int kt = 0; kt < KT; kt++) {
        __syncthreads();
        if (kt + 1 < KT) {
            int nb = (kt + 1) & 1, k0 = (kt + 1) * GBK;
#pragma unroll
            for (int q = 0; q < RF; q++) {
                const ushort* gp = A + (size_t)(m0 + wave * RF * 16 + q * 16 + srow) * K + k0 + schunk;
                gl2lds(gp, &As[nb][(wave * RF * 16 + q * 16) * GBK]);
            }
            const ushort* gb = Wt + (size_t)(n0 + wave * 16 + srow) * K + k0 + schunk;
            gl2lds(gb, &Bs[nb][wave * 16 * GBK]);
        }
        int b = kt & 1;
        bf16x8 af[RF];
#pragma unroll
        for (int rf = 0; rf < RF; rf++)
            af[rf] = *(const bf16x8*)&As[b][(wave * RF * 16 + rf * 16 + lrow) * GBK + lq * 8];
#pragma unroll
        for (int ng = 0; ng < 4; ng++) {
            bf16x8 bf = *(const bf16x8*)&Bs[b][(ng * 16 + lrow) * GBK + lq * 8];
#pragma unroll
            for (int rf = 0; rf < RF; rf++)
                acc[rf][ng] = __builtin_amdgcn_mfma_f32_16x16x32_bf16(af[rf], bf, acc[rf][ng], 0, 0, 0);
        }
    }
    // epilogue: C/D layout col=lane&15 (within ng group), row=lq*4+r
#pragma unroll
    for (int rf = 0; rf < RF; rf++)
#pragma unroll
        for (int ng = 0; ng < 4; ng++)
#pragma unroll
            for (int r = 0; r < 4; r++) {
                int row = m0 + wave * RF * 16 + rf * 16 + lq * 4 + r;
                int colI = n0 + ng * 16 + lrow;
                if (row < M && colI < N) {
                    if constexpr (OM == 0)
                        ((__hip_bfloat16*)Cv)[(size_t)row * N + colI] = __float2bfloat16(acc[rf][ng][r]);
                    else
                        ((unsigned char*)Cv)[(size_t)row * N + colI] = f2fp8(acc[rf][ng][r]);
                }
            }
    if constexpr (DOA == 2) {
        float as_l[2], ad_l[2];
#pragma unroll
        for (int ng = 0; ng < 2; ng++) {
            as_l[ng] = Asrc[ng * 16 + lrow];
            ad_l[ng] = Adst[ng * 16 + lrow];
        }
#pragma unroll
        for (int rf = 0; rf < RF; rf++)
#pragma unroll
            for (int r = 0; r < 4; r++) {
                float ps = acc[rf][0][r] * as_l[0] + acc[rf][1][r] * as_l[1];
                float pd = acc[rf][0][r] * ad_l[0] + acc[rf][1][r] * ad_l[1];
#pragma unroll
                for (int o = 1; o < 16; o <<= 1) {
                    ps += __shfl_xor(ps, o);
                    pd += __shfl_xor(pd, o);
                }
                int row = m0 + wave * RF * 16 + rf * 16 + lq * 4 + r;
                if (lrow == 0 && row < M) {
                    as8[(size_t)row * 8] = ps;
                    ad8[(size_t)row * 8] = pd;
                }
            }
    }
}

// ---------------------------------------------------------------- Phase C: wave-per-dst, fp8 h-table gather
// R7 version (66.9us): index preload + readlane -> zero dependent loads in inner loop;
// 2-deep gather pipeline; NT on streaming colA/out. At its memory-path floor
// (~211MB fetch @ ~3.9TB/s); VALU/latency surgery is neutral-to-negative (R8).
__global__ void gat_aggC7_kernel(const int* __restrict__ rp, const int* __restrict__ colA,
                                 const float* __restrict__ as8, const float* __restrict__ ad8,
                                 const unsigned char* __restrict__ h8,
                                 const float* __restrict__ bias,
                                 __hip_bfloat16* __restrict__ outp) {
    int d = blockIdx.x * 4 + (threadIdx.x >> 6);
    if (d >= NN) return;
    int lane = threadIdx.x & 63;
    int lc = (lane < 56) ? lane : 55;           // clamp: lanes 56-63 duplicate lane 55
    unsigned hh = (unsigned)(lc >> 3);
    unsigned lb = (unsigned)lc * 8u;
    float adh = ad8[(size_t)d * 8 + hh];
    int s0 = rp[d], s1 = rp[d + 1];
    int s1m1 = s1 - 1;
    f32x2 a01 = {0.f, 0.f}, a23 = {0.f, 0.f}, a45 = {0.f, 0.f}, a67 = {0.f, 0.f};
    float den = 0.f;

#define GATHER4(B4, ASV, HV) do {                                      \
        _Pragma("unroll")                                              \
        for (int k_ = 0; k_ < 4; k_++) {                               \
            unsigned s_ = (unsigned)__builtin_amdgcn_readlane(myIdx, (B4) + k_); \
            ASV[k_] = as8[s_ * 8u + hh];                               \
            HV[k_] = *(const uint2*)(h8 + (s_ * 448u + lb));           \
        }                                                              \
    } while (0)

#define CONSUME(ASV, HV, JJ) do {                                      \
        float w_[4];                                                   \
        _Pragma("unroll")                                              \
        for (int k_ = 0; k_ < 4; k_++) {                               \
            float e_ = ASV[k_] + adh;                                  \
            e_ = (e_ > 0.f) ? e_ : 0.2f * e_;                          \
            float ww_ = __expf(e_);                                    \
            ww_ = ((JJ) + k_ < s1) ? ww_ : 0.f;                        \
            w_[k_] = ww_;                                              \
            den += ww_;                                                \
        }                                                              \
        _Pragma("unroll")                                              \
        for (int k_ = 0; k_ < 4; k_++) {                               \
            f32x2 w2_ = {w_[k_], w_[k_]};                              \
            fp8acc_pk(HV[k_].x, w2_, a01, a23);                        \
            fp8acc_pk(HV[k_].y, w2_, a45, a67);                        \
        }                                                              \
    } while (0)

    // chunked over 64-edge windows (deg > 64 essentially never occurs; loop is correctness armor)
    for (int base = s0; base < s1; base += 64) {
        int myIdx = __builtin_nontemporal_load(colA + (unsigned)min(base + lane, s1m1));
        int cnt = min(s1 - base, 64);
        int nb = (cnt + 3) >> 2;                              // >=1
        int jb = base;
        int b4 = 0;
        float as0v[4], as1v[4];
        uint2 hv0[4], hv1[4];
        GATHER4(0, as0v, hv0);
        int rem = nb - 1;
        while (rem >= 2) {
            GATHER4(b4 + 4, as1v, hv1); CONSUME(as0v, hv0, jb); jb += 4;
            GATHER4(b4 + 8, as0v, hv0); CONSUME(as1v, hv1, jb); jb += 4;
            b4 += 8; rem -= 2;
        }
        if (rem == 1) {
            GATHER4(b4 + 4, as1v, hv1); CONSUME(as0v, hv0, jb); jb += 4;
            CONSUME(as1v, hv1, jb);
        } else {
            CONSUME(as0v, hv0, jb);
        }
    }
#undef GATHER4
#undef CONSUME

    float inv = 1.f / (den + 1e-16f);
    const float4* bp = (const float4*)(bias + lb);
    float4 bb0 = bp[0], bb1 = bp[1];
    float bv[8] = {bb0.x, bb0.y, bb0.z, bb0.w, bb1.x, bb1.y, bb1.z, bb1.w};
    float av[8] = {a01.x, a01.y, a23.x, a23.y, a45.x, a45.y, a67.x, a67.y};
    ushort o8[8];
#pragma unroll
    for (int k = 0; k < 8; k++) {
        float o = av[k] * inv + bv[k];
        o = fmaxf(o, 0.f);
        o8[k] = f2bu(o);
    }
    if (lane < 56) {
        u32x4 ov = *(const u32x4*)o8;
        __builtin_nontemporal_store(ov, (u32x4*)((ushort*)outp + (size_t)d * 448 + lane * 8));
    }
}

// ---------------------------------------------------------------- Phase C final: 2 dsts/wave, 32 ch (bf16 h), log_softmax
__global__ void gat_aggCF_kernel(const int* __restrict__ rp, const int* __restrict__ colA,
                                 const float* __restrict__ as8, const float* __restrict__ ad8,
                                 const __hip_bfloat16* __restrict__ h,
                                 const float* __restrict__ bias,
                                 float* __restrict__ outp) {
    int wid = blockIdx.x * 4 + (threadIdx.x >> 6);
    int lane = threadIdx.x & 63;
    int half = lane >> 5;
    unsigned c = (unsigned)(lane & 31);
    int dreal = wid * 2 + half;
    bool valid = dreal < NN;
    int d = valid ? dreal : (NN - 1);
    float adh = ad8[(size_t)d * 8];
    int s0 = rp[d], s1 = rp[d + 1];
    float acc = 0.f, den = 0.f;
    int j = s0;
    for (; j + 2 <= s1; j += 2) {
        unsigned ju = (unsigned)j;
        unsigned sA = (unsigned)__builtin_nontemporal_load(colA + ju);
        unsigned sB = (unsigned)__builtin_nontemporal_load(colA + ju + 1);
        float eA = as8[sA * 8u] + adh;
        float eB = as8[sB * 8u] + adh;
        float vA = bf2f(h[sA * 32u + c]);
        float vB = bf2f(h[sB * 32u + c]);
        eA = (eA > 0.f) ? eA : 0.2f * eA;
        eB = (eB > 0.f) ? eB : 0.2f * eB;
        float wA = __expf(eA), wB = __expf(eB);
        den += wA + wB;
        acc += wA * vA + wB * vB;
    }
    for (; j < s1; j++) {
        unsigned s = (unsigned)__builtin_nontemporal_load(colA + (unsigned)j);
        float e = as8[s * 8u] + adh;
        e = (e > 0.f) ? e : 0.2f * e;
        float w = __expf(e);
        den += w;
        acc += w * bf2f(h[s * 32u + c]);
    }
    float o = acc / (den + 1e-16f) + bias[c];
    float t = o;
#pragma unroll
    for (int off = 16; off > 0; off >>= 1) t = fmaxf(t, __shfl_xor(t, off));
    float ex = __expf(o - t);
#pragma unroll
    for (int off = 16; off > 0; off >>= 1) ex += __shfl_xor(ex, off);
    float res = o - t - __logf(ex);
    if (valid) __builtin_nontemporal_store(res, &outp[(size_t)d * 32 + c]);
}

// ---------------------------------------------------------------- launch
extern "C" void kernel_launch(void* const* d_in, const int* in_sizes, int n_in,
                              void* d_out, int out_size, void* d_ws, size_t ws_size,
                              hipStream_t stream) {
    const float* x   = (const float*)d_in[0];
    const int*   ei  = (const int*)d_in[1];
    const float* W1  = (const float*)d_in[2];
    const float* a1s = (const float*)d_in[3];
    const float* a1d = (const float*)d_in[4];
    const float* b1  = (const float*)d_in[5];
    const float* W2  = (const float*)d_in[6];
    const float* a2s = (const float*)d_in[7];
    const float* a2d = (const float*)d_in[8];
    const float* b2  = (const float*)d_in[9];
    const float* W3  = (const float*)d_in[10];
    const float* a3s = (const float*)d_in[11];
    const float* a3d = (const float*)d_in[12];
    const float* b3  = (const float*)d_in[13];
    float* out = (float*)d_out;

    // workspace layout (~105 MB)
    char* w = (char*)d_ws;
    unsigned char* hbuf8 = (unsigned char*)w;                  // NP*448 fp8 (22.5 MB); layer-3 reuses as bf16 NP*32
    __hip_bfloat16* hbuf3 = (__hip_bfloat16*)w;
    ushort* xb = (ushort*)(w + (size_t)NP * 448);              // NP*256 bf16 (25.7 MB)
    __hip_bfloat16* act = (__hip_bfloat16*)(xb + (size_t)NP * 256);  // NP*448 bf16 (44.9 MB)
    float* as8 = (float*)(act + (size_t)NP * 448);             // N*8 f32
    float* ad8 = as8 + (size_t)NN * 8;                         // N*8 f32
    int* cnt     = (int*)(ad8 + (size_t)NN * 8);               // N
    int* fillc   = cnt + NN;                                   // N
    int* row_ptr = fillc + NN;                                 // N+4 (padded)
    int* tmp     = row_ptr + (NN + 4);                         // N
    int* part    = tmp + NN;                                   // 256
    int* colA    = part + 256;                                 // ET
    char* pw = (char*)(colA + ET);
    pw = (char*)(((uintptr_t)pw + 15) & ~(uintptr_t)15);
    ushort* Wt1 = (ushort*)pw;                                 // 448*256
    ushort* Wt2 = Wt1 + 448 * 256;                             // 448*448
    ushort* Wt3 = Wt2 + 448 * 448;                             // 64*448 (rows 32..63 poison, never stored)

    hipMemsetAsync(cnt, 0, 2 * (size_t)NN * sizeof(int), stream);  // cnt + fillc

    // fused prep (wt x3 + x->bf16) + CSR count
    gat_prepcnt_kernel<<<PBLK + CBLK, 256, 0, stream>>>(W1, W2, W3, x, Wt1, Wt2, Wt3, xb, ei, cnt);
    gat_scan1_kernel<<<NB_SCAN, 256, 0, stream>>>(cnt, tmp, part);
    gat_scan2_kernel<<<1, 256, 0, stream>>>(part);
    gat_scan3_kernel<<<NB_SCAN, 256, 0, stream>>>(tmp, part, row_ptr);
    gat_fill_kernel<<<CBLK, 256, 0, stream>>>(ei, row_ptr, fillc, colA);

    dim3 gemmBlk(256);
    int mtilesF = NP / 64;              // 784 (fused-head GEMM, layers 1&2; also layer-3 RF=1)
    int aggBlocks = (NN + 3) / 4;       // 12500

    // --- layer 1 (fused heads; alpha fused; h written as fp8)
    gat_gemmF_kernel<<<mtilesF, gemmBlk, 0, stream>>>(
        xb, Wt1, hbuf8, a1s, a1d, as8, ad8, 256);
    gat_aggC7_kernel<<<aggBlocks, 256, 0, stream>>>(row_ptr, colA, as8, ad8, hbuf8, b1, act);

    // --- layer 2
    gat_gemmF_kernel<<<mtilesF, gemmBlk, 0, stream>>>(
        (const ushort*)act, Wt2, hbuf8, a2s, a2d, as8, ad8, 448);
    gat_aggC7_kernel<<<aggBlocks, 256, 0, stream>>>(row_ptr, colA, as8, ad8, hbuf8, b2, act);

    // --- layer 3 (1 head, 32 ch, alpha fused, bf16 h, RF=1 for occupancy, log_softmax, fp32 out)
    gat_gemm_kernel<1, 2, 0><<<dim3(mtilesF, 1), gemmBlk, 0, stream>>>(
        (const ushort*)act, Wt3, hbuf3, a3s, a3d, as8, ad8, NN, 448, 32);
    int fBlocks = (NN + 7) / 8;  // 8 dsts per block (2 per wave)
    gat_aggCF_kernel<<<fBlocks, 256, 0, stream>>>(row_ptr, colA, as8, ad8, hbuf3, b3, out);
}

// Round 10
// 511.548 us; speedup vs baseline: 1.0061x; 1.0061x over previous
//
#include <hip/hip_runtime.h>
#include <hip/hip_bf16.h>
#include <hip/hip_fp16.h>

#define NN 50000
#define NP 50176              // NN padded to multiple of 256 (GEMM tiles, no bounds checks)
#define EE 800000
#define ET (EE + NN)          // 850000 edges incl self-loops
#define NB_SCAN ((NN + 255) / 256)   // 196

typedef __attribute__((ext_vector_type(8))) short bf16x8;
typedef __attribute__((ext_vector_type(4))) float f32x4;
typedef __attribute__((ext_vector_type(2))) float f32x2;
typedef __attribute__((ext_vector_type(4))) unsigned int u32x4;

static __device__ __forceinline__ float bf2f(__hip_bfloat16 x) { return __bfloat162float(x); }
static __device__ __forceinline__ ushort f2bu(float f) {
    union { __hip_bfloat16 b; ushort u; } c;
    c.b = __float2bfloat16(f);
    return c.u;
}
static __device__ __forceinline__ float u2f(ushort u) {
    union { ushort u; __hip_bfloat16 b; } c;
    c.u = u;
    return __bfloat162float(c.b);
}
// fp8 e4m3 HW conversion (gfx950). Encode+decode use the same HW format -> self-consistent.
static __device__ __forceinline__ unsigned char f2fp8(float v) {
    int p = __builtin_amdgcn_cvt_pk_fp8_f32(v, v, 0, false);
    return (unsigned char)(p & 0xff);
}
// decode 4 packed fp8 bytes -> two f32 pairs, packed-FMA (v_pk_fma_f32) into two f32x2 accumulators.
static __device__ __forceinline__ void fp8acc_pk(unsigned v, f32x2 w2, f32x2& a01, f32x2& a23) {
#if __has_builtin(__builtin_amdgcn_cvt_pk_f32_fp8)
    f32x2 f01 = __builtin_amdgcn_cvt_pk_f32_fp8((int)v, false);
    f32x2 f23 = __builtin_amdgcn_cvt_pk_f32_fp8((int)v, true);
#else
    f32x2 f01 = { __builtin_amdgcn_cvt_f32_fp8(v, 0), __builtin_amdgcn_cvt_f32_fp8(v, 1) };
    f32x2 f23 = { __builtin_amdgcn_cvt_f32_fp8(v, 2), __builtin_amdgcn_cvt_f32_fp8(v, 3) };
#endif
    asm("v_pk_fma_f32 %0, %1, %2, %0" : "+v"(a01) : "v"(f01), "v"(w2));
    asm("v_pk_fma_f32 %0, %1, %2, %0" : "+v"(a23) : "v"(f23), "v"(w2));
}
// async global->LDS DMA, 16B per lane; lds dest must be wave-uniform base
static __device__ __forceinline__ void gl2lds(const ushort* g, ushort* l) {
    __builtin_amdgcn_global_load_lds(
        (const __attribute__((address_space(1))) void*)g,
        (__attribute__((address_space(3))) void*)l,
        16, 0, 0);
}

// ---------------------------------------------------------------- fused prep + CSR count
#define PA1 (256 * 448)
#define PA2 (448 * 448)
#define PA3 (448 * 32)
#define PXQ (NN * 64)   // x quads (256 ch / 4)
#define PTOT (PA1 + PA2 + PA3 + PXQ)
#define PBLK ((PTOT + 255) / 256)
#define CBLK ((ET + 255) / 256)

__global__ void gat_prepcnt_kernel(const float* __restrict__ W1, const float* __restrict__ W2,
                                   const float* __restrict__ W3, const float* __restrict__ x,
                                   ushort* __restrict__ Wt1, ushort* __restrict__ Wt2,
                                   ushort* __restrict__ Wt3, ushort* __restrict__ xb,
                                   const int* __restrict__ ei, int* __restrict__ cnt) {
    int b = blockIdx.x;
    if (b >= PBLK) {
        int i = (b - PBLK) * 256 + threadIdx.x;
        if (i < ET) {
            int dst = (i < EE) ? ei[EE + i] : (i - EE);
            atomicAdd(&cnt[dst], 1);
        }
        return;
    }
    int i = b * 256 + threadIdx.x;
    if (i < PA1) {
        int k = i / 448, n = i - k * 448;
        Wt1[(size_t)n * 256 + k] = f2bu(W1[i]);
        return;
    }
    i -= PA1;
    if (i < PA2) {
        int k = i / 448, n = i - k * 448;
        Wt2[(size_t)n * 448 + k] = f2bu(W2[i]);
        return;
    }
    i -= PA2;
    if (i < PA3) {
        int k = i / 32, n = i - k * 32;
        Wt3[(size_t)n * 448 + k] = f2bu(W3[i]);
        return;
    }
    i -= PA3;
    if (i < PXQ) {
        float4 f = ((const float4*)x)[i];
        ushort u[4] = {f2bu(f.x), f2bu(f.y), f2bu(f.z), f2bu(f.w)};
        ((uint2*)xb)[i] = *(const uint2*)u;
    }
}

// ---------------------------------------------------------------- CSR scans + fill
__global__ void gat_scan1_kernel(const int* __restrict__ cnt, int* __restrict__ tmp,
                                 int* __restrict__ part) {
    __shared__ int sm[256];
    int tid = threadIdx.x;
    int i = blockIdx.x * 256 + tid;
    int v = (i < NN) ? cnt[i] : 0;
    sm[tid] = v;
    __syncthreads();
    for (int o = 1; o < 256; o <<= 1) {
        int t = (tid >= o) ? sm[tid - o] : 0;
        __syncthreads();
        sm[tid] += t;
        __syncthreads();
    }
    if (i < NN) tmp[i] = sm[tid];
    if (tid == 255) part[blockIdx.x] = sm[255];
}

__global__ void gat_scan2_kernel(int* __restrict__ part) {
    __shared__ int sm[256];
    int tid = threadIdx.x;
    int v = (tid < NB_SCAN) ? part[tid] : 0;
    sm[tid] = v;
    __syncthreads();
    for (int o = 1; o < 256; o <<= 1) {
        int t = (tid >= o) ? sm[tid - o] : 0;
        __syncthreads();
        sm[tid] += t;
        __syncthreads();
    }
    part[tid] = sm[tid];
}

__global__ void gat_scan3_kernel(const int* __restrict__ tmp, const int* __restrict__ part,
                                 int* __restrict__ row_ptr) {
    int i = blockIdx.x * 256 + threadIdx.x;
    int off = (blockIdx.x > 0) ? part[blockIdx.x - 1] : 0;
    if (i < NN) row_ptr[i + 1] = tmp[i] + off;
    if (i == 0) row_ptr[0] = 0;
}

__global__ void gat_fill_kernel(const int* __restrict__ ei, const int* __restrict__ row_ptr,
                                int* __restrict__ fillc, int* __restrict__ colA) {
    int i = blockIdx.x * blockDim.x + threadIdx.x;
    if (i >= ET) return;
    int s, d;
    if (i < EE) { s = ei[i]; d = ei[EE + i]; }
    else        { s = d = i - EE; }
    int pos = row_ptr[d] + atomicAdd(&fillc[d], 1);
    colA[pos] = s;
}

// ---------------------------------------------------------------- Fused-head GEMM (layers 1 & 2)
// One block = 64 rows x ALL 448 cols. Per K-step: one 64x32 A-tile + full 448x32 B-slab.
// LDS XOR chunk-swizzle (T2, rule #21: linear gl2lds dest + inverse-swizzled GLOBAL source
// + swizzled READ): lane l stages global 16B-chunk (l&3)^((l>>3)&3) of its 64B row, so
// LDS[row][c] = G[c ^ ((row>>1)&3)]; fragment read uses chunk lq ^ ((lrow>>1)&3) -> G[lq].
// Kills the stride-64B 16-lane ds_read_b128 conflict (R9: 5.09M conflict-cycles, 85% of
// kernel time): post-swizzle each 8-lane batch hits all 8 distinct 16B bank-groups.
// Bit-identical data; same accumulation order -> bitwise-identical output.
__global__ __launch_bounds__(256) void gat_gemmF_kernel(
    const ushort* __restrict__ A, const ushort* __restrict__ Wt,
    unsigned char* __restrict__ C8,
    const float* __restrict__ Asrc, const float* __restrict__ Adst,
    float* __restrict__ as8, float* __restrict__ ad8,
    int K) {
    __shared__ __align__(16) ushort As[2][64 * 32];     // 8 KB
    __shared__ __align__(16) ushort Bs[2][448 * 32];    // 56 KB
    int tid = threadIdx.x;
    int wave = tid >> 6, lane = tid & 63;
    int lrow = lane & 15, lq = lane >> 4;
    int m0 = blockIdx.x * 64;
    int srow = lane >> 2;
    int schunk = ((lane & 3) ^ ((lane >> 3) & 3)) * 8;  // inverse-swizzled global chunk
    int swz = (lrow >> 1) & 3;                          // read-side swizzle
    f32x4 acc[7][4] = {};

    int KT = K / 32;
    {
        const ushort* gp = A + (size_t)(m0 + wave * 16 + srow) * K + schunk;
        gl2lds(gp, &As[0][(wave * 16) * 32]);
#pragma unroll
        for (int q = 0; q < 7; q++) {
            const ushort* gb = Wt + (size_t)(wave * 112 + q * 16 + srow) * K + schunk;
            gl2lds(gb, &Bs[0][(wave * 112 + q * 16) * 32]);
        }
    }
    for (int kt = 0; kt < KT; kt++) {
        __syncthreads();
        if (kt + 1 < KT) {
            int nb = (kt + 1) & 1, k0 = (kt + 1) * 32;
            const ushort* gp = A + (size_t)(m0 + wave * 16 + srow) * K + k0 + schunk;
            gl2lds(gp, &As[nb][(wave * 16) * 32]);
#pragma unroll
            for (int q = 0; q < 7; q++) {
                const ushort* gb = Wt + (size_t)(wave * 112 + q * 16 + srow) * K + k0 + schunk;
                gl2lds(gb, &Bs[nb][(wave * 112 + q * 16) * 32]);
            }
        }
        int b = kt & 1;
        bf16x8 af = *(const bf16x8*)&As[b][(wave * 16 + lrow) * 32 + (lq ^ swz) * 8];
#pragma unroll
        for (int h = 0; h < 7; h++)
#pragma unroll
            for (int ng = 0; ng < 4; ng++) {
                bf16x8 bf = *(const bf16x8*)&Bs[b][(h * 64 + ng * 16 + lrow) * 32 + (lq ^ swz) * 8];
                acc[h][ng] = __builtin_amdgcn_mfma_f32_16x16x32_bf16(af, bf, acc[h][ng], 0, 0, 0);
            }
    }
    // C-write: fp8; C/D layout col=lane&15 within ng group, row=lq*4+r
#pragma unroll
    for (int h = 0; h < 7; h++)
#pragma unroll
        for (int ng = 0; ng < 4; ng++)
#pragma unroll
            for (int r = 0; r < 4; r++) {
                int row = m0 + wave * 16 + lq * 4 + r;
                int col = h * 64 + ng * 16 + lrow;
                if (row < NN)
                    C8[(size_t)row * 448 + col] = f2fp8(acc[h][ng][r]);
            }
    // fused alpha: per head, ps/pd partial over 4 ng, 16-lane shfl reduce (same order as before)
#pragma unroll
    for (int h = 0; h < 7; h++) {
        float as_l[4], ad_l[4];
#pragma unroll
        for (int ng = 0; ng < 4; ng++) {
            as_l[ng] = Asrc[h * 64 + ng * 16 + lrow];
            ad_l[ng] = Adst[h * 64 + ng * 16 + lrow];
        }
#pragma unroll
        for (int r = 0; r < 4; r++) {
            float ps = 0.f, pd = 0.f;
#pragma unroll
            for (int ng = 0; ng < 4; ng++) {
                ps += acc[h][ng][r] * as_l[ng];
                pd += acc[h][ng][r] * ad_l[ng];
            }
#pragma unroll
            for (int o = 1; o < 16; o <<= 1) {
                ps += __shfl_xor(ps, o);
                pd += __shfl_xor(pd, o);
            }
            int row = m0 + wave * 16 + lq * 4 + r;
            if (lrow == 0 && row < NN) {
                as8[(size_t)row * 8 + h] = ps;
                ad8[(size_t)row * 8 + h] = pd;
            }
        }
    }
}

// ---------------------------------------------------------------- GEMM core (layer 3 only: DOA=2, bf16 out)
#define GBN 64
#define GBK 32

template <int RF, int DOA, int OM>
__global__ __launch_bounds__(256) void gat_gemm_kernel(
    const ushort* __restrict__ A, const ushort* __restrict__ Wt,
    void* __restrict__ Cv,
    const float* __restrict__ Asrc, const float* __restrict__ Adst,
    float* __restrict__ as8, float* __restrict__ ad8,
    int M, int K, int N) {
    constexpr int GBM = RF * 64;
    __shared__ __align__(16) ushort As[2][GBM * GBK];
    __shared__ __align__(16) ushort Bs[2][GBN * GBK];
    int tid = threadIdx.x;
    int wave = tid >> 6, lane = tid & 63;
    int lrow = lane & 15, lq = lane >> 4;
    int mt = blockIdx.x, head = blockIdx.y;
    int m0 = mt * GBM, n0 = head * GBN;

    int srow = lane >> 2, schunk = (lane & 3) * 8;      // 4 lanes per 64B row-chunk
    f32x4 acc[RF][4] = {};

    int KT = K / GBK;
    {
#pragma unroll
        for (int q = 0; q < RF; q++) {
            const ushort* gp = A + (size_t)(m0 + wave * RF * 16 + q * 16 + srow) * K + schunk;
            gl2lds(gp, &As[0][(wave * RF * 16 + q * 16) * GBK]);
        }
        const ushort* gb = Wt + (size_t)(n0 + wave * 16 + srow) * K + schunk;
        gl2lds(gb, &Bs[0][wave * 16 * GBK]);
    }
    for (int kt = 0; kt < KT; kt++) {
        __syncthreads();
        if (kt + 1 < KT) {
            int nb = (kt + 1) & 1, k0 = (kt + 1) * GBK;
#pragma unroll
            for (int q = 0; q < RF; q++) {
                const ushort* gp = A + (size_t)(m0 + wave * RF * 16 + q * 16 + srow) * K + k0 + schunk;
                gl2lds(gp, &As[nb][(wave * RF * 16 + q * 16) * GBK]);
            }
            const ushort* gb = Wt + (size_t)(n0 + wave * 16 + srow) * K + k0 + schunk;
            gl2lds(gb, &Bs[nb][wave * 16 * GBK]);
        }
        int b = kt & 1;
        bf16x8 af[RF];
#pragma unroll
        for (int rf = 0; rf < RF; rf++)
            af[rf] = *(const bf16x8*)&As[b][(wave * RF * 16 + rf * 16 + lrow) * GBK + lq * 8];
#pragma unroll
        for (int ng = 0; ng < 4; ng++) {
            bf16x8 bf = *(const bf16x8*)&Bs[b][(ng * 16 + lrow) * GBK + lq * 8];
#pragma unroll
            for (int rf = 0; rf < RF; rf++)
                acc[rf][ng] = __builtin_amdgcn_mfma_f32_16x16x32_bf16(af[rf], bf, acc[rf][ng], 0, 0, 0);
        }
    }
    // epilogue: C/D layout col=lane&15 (within ng group), row=lq*4+r
#pragma unroll
    for (int rf = 0; rf < RF; rf++)
#pragma unroll
        for (int ng = 0; ng < 4; ng++)
#pragma unroll
            for (int r = 0; r < 4; r++) {
                int row = m0 + wave * RF * 16 + rf * 16 + lq * 4 + r;
                int colI = n0 + ng * 16 + lrow;
                if (row < M && colI < N) {
                    if constexpr (OM == 0)
                        ((__hip_bfloat16*)Cv)[(size_t)row * N + colI] = __float2bfloat16(acc[rf][ng][r]);
                    else
                        ((unsigned char*)Cv)[(size_t)row * N + colI] = f2fp8(acc[rf][ng][r]);
                }
            }
    if constexpr (DOA == 2) {
        float as_l[2], ad_l[2];
#pragma unroll
        for (int ng = 0; ng < 2; ng++) {
            as_l[ng] = Asrc[ng * 16 + lrow];
            ad_l[ng] = Adst[ng * 16 + lrow];
        }
#pragma unroll
        for (int rf = 0; rf < RF; rf++)
#pragma unroll
            for (int r = 0; r < 4; r++) {
                float ps = acc[rf][0][r] * as_l[0] + acc[rf][1][r] * as_l[1];
                float pd = acc[rf][0][r] * ad_l[0] + acc[rf][1][r] * ad_l[1];
#pragma unroll
                for (int o = 1; o < 16; o <<= 1) {
                    ps += __shfl_xor(ps, o);
                    pd += __shfl_xor(pd, o);
                }
                int row = m0 + wave * RF * 16 + rf * 16 + lq * 4 + r;
                if (lrow == 0 && row < M) {
                    as8[(size_t)row * 8] = ps;
                    ad8[(size_t)row * 8] = pd;
                }
            }
    }
}

// ---------------------------------------------------------------- Phase C: wave-per-dst, fp8 h-table gather
// R7 version (66.9us): index preload + readlane -> zero dependent loads in inner loop;
// 2-deep gather pipeline; NT on streaming colA/out. At its memory-path floor
// (~211MB fetch @ ~3.9TB/s); VALU/latency surgery is neutral-to-negative (R8).
__global__ void gat_aggC7_kernel(const int* __restrict__ rp, const int* __restrict__ colA,
                                 const float* __restrict__ as8, const float* __restrict__ ad8,
                                 const unsigned char* __restrict__ h8,
                                 const float* __restrict__ bias,
                                 __hip_bfloat16* __restrict__ outp) {
    int d = blockIdx.x * 4 + (threadIdx.x >> 6);
    if (d >= NN) return;
    int lane = threadIdx.x & 63;
    int lc = (lane < 56) ? lane : 55;           // clamp: lanes 56-63 duplicate lane 55
    unsigned hh = (unsigned)(lc >> 3);
    unsigned lb = (unsigned)lc * 8u;
    float adh = ad8[(size_t)d * 8 + hh];
    int s0 = rp[d], s1 = rp[d + 1];
    int s1m1 = s1 - 1;
    f32x2 a01 = {0.f, 0.f}, a23 = {0.f, 0.f}, a45 = {0.f, 0.f}, a67 = {0.f, 0.f};
    float den = 0.f;

#define GATHER4(B4, ASV, HV) do {                                      \
        _Pragma("unroll")                                              \
        for (int k_ = 0; k_ < 4; k_++) {                               \
            unsigned s_ = (unsigned)__builtin_amdgcn_readlane(myIdx, (B4) + k_); \
            ASV[k_] = as8[s_ * 8u + hh];                               \
            HV[k_] = *(const uint2*)(h8 + (s_ * 448u + lb));           \
        }                                                              \
    } while (0)

#define CONSUME(ASV, HV, JJ) do {                                      \
        float w_[4];                                                   \
        _Pragma("unroll")                                              \
        for (int k_ = 0; k_ < 4; k_++) {                               \
            float e_ = ASV[k_] + adh;                                  \
            e_ = (e_ > 0.f) ? e_ : 0.2f * e_;                          \
            float ww_ = __expf(e_);                                    \
            ww_ = ((JJ) + k_ < s1) ? ww_ : 0.f;                        \
            w_[k_] = ww_;                                              \
            den += ww_;                                                \
        }                                                              \
        _Pragma("unroll")                                              \
        for (int k_ = 0; k_ < 4; k_++) {                               \
            f32x2 w2_ = {w_[k_], w_[k_]};                              \
            fp8acc_pk(HV[k_].x, w2_, a01, a23);                        \
            fp8acc_pk(HV[k_].y, w2_, a45, a67);                        \
        }                                                              \
    } while (0)

    // chunked over 64-edge windows (deg > 64 essentially never occurs; loop is correctness armor)
    for (int base = s0; base < s1; base += 64) {
        int myIdx = __builtin_nontemporal_load(colA + (unsigned)min(base + lane, s1m1));
        int cnt = min(s1 - base, 64);
        int nb = (cnt + 3) >> 2;                              // >=1
        int jb = base;
        int b4 = 0;
        float as0v[4], as1v[4];
        uint2 hv0[4], hv1[4];
        GATHER4(0, as0v, hv0);
        int rem = nb - 1;
        while (rem >= 2) {
            GATHER4(b4 + 4, as1v, hv1); CONSUME(as0v, hv0, jb); jb += 4;
            GATHER4(b4 + 8, as0v, hv0); CONSUME(as1v, hv1, jb); jb += 4;
            b4 += 8; rem -= 2;
        }
        if (rem == 1) {
            GATHER4(b4 + 4, as1v, hv1); CONSUME(as0v, hv0, jb); jb += 4;
            CONSUME(as1v, hv1, jb);
        } else {
            CONSUME(as0v, hv0, jb);
        }
    }
#undef GATHER4
#undef CONSUME

    float inv = 1.f / (den + 1e-16f);
    const float4* bp = (const float4*)(bias + lb);
    float4 bb0 = bp[0], bb1 = bp[1];
    float bv[8] = {bb0.x, bb0.y, bb0.z, bb0.w, bb1.x, bb1.y, bb1.z, bb1.w};
    float av[8] = {a01.x, a01.y, a23.x, a23.y, a45.x, a45.y, a67.x, a67.y};
    ushort o8[8];
#pragma unroll
    for (int k = 0; k < 8; k++) {
        float o = av[k] * inv + bv[k];
        o = fmaxf(o, 0.f);
        o8[k] = f2bu(o);
    }
    if (lane < 56) {
        u32x4 ov = *(const u32x4*)o8;
        __builtin_nontemporal_store(ov, (u32x4*)((ushort*)outp + (size_t)d * 448 + lane * 8));
    }
}

// ---------------------------------------------------------------- Phase C final: 2 dsts/wave, 32 ch (bf16 h), log_softmax
__global__ void gat_aggCF_kernel(const int* __restrict__ rp, const int* __restrict__ colA,
                                 const float* __restrict__ as8, const float* __restrict__ ad8,
                                 const __hip_bfloat16* __restrict__ h,
                                 const float* __restrict__ bias,
                                 float* __restrict__ outp) {
    int wid = blockIdx.x * 4 + (threadIdx.x >> 6);
    int lane = threadIdx.x & 63;
    int half = lane >> 5;
    unsigned c = (unsigned)(lane & 31);
    int dreal = wid * 2 + half;
    bool valid = dreal < NN;
    int d = valid ? dreal : (NN - 1);
    float adh = ad8[(size_t)d * 8];
    int s0 = rp[d], s1 = rp[d + 1];
    float acc = 0.f, den = 0.f;
    int j = s0;
    for (; j + 2 <= s1; j += 2) {
        unsigned ju = (unsigned)j;
        unsigned sA = (unsigned)__builtin_nontemporal_load(colA + ju);
        unsigned sB = (unsigned)__builtin_nontemporal_load(colA + ju + 1);
        float eA = as8[sA * 8u] + adh;
        float eB = as8[sB * 8u] + adh;
        float vA = bf2f(h[sA * 32u + c]);
        float vB = bf2f(h[sB * 32u + c]);
        eA = (eA > 0.f) ? eA : 0.2f * eA;
        eB = (eB > 0.f) ? eB : 0.2f * eB;
        float wA = __expf(eA), wB = __expf(eB);
        den += wA + wB;
        acc += wA * vA + wB * vB;
    }
    for (; j < s1; j++) {
        unsigned s = (unsigned)__builtin_nontemporal_load(colA + (unsigned)j);
        float e = as8[s * 8u] + adh;
        e = (e > 0.f) ? e : 0.2f * e;
        float w = __expf(e);
        den += w;
        acc += w * bf2f(h[s * 32u + c]);
    }
    float o = acc / (den + 1e-16f) + bias[c];
    float t = o;
#pragma unroll
    for (int off = 16; off > 0; off >>= 1) t = fmaxf(t, __shfl_xor(t, off));
    float ex = __expf(o - t);
#pragma unroll
    for (int off = 16; off > 0; off >>= 1) ex += __shfl_xor(ex, off);
    float res = o - t - __logf(ex);
    if (valid) __builtin_nontemporal_store(res, &outp[(size_t)d * 32 + c]);
}

// ---------------------------------------------------------------- launch
extern "C" void kernel_launch(void* const* d_in, const int* in_sizes, int n_in,
                              void* d_out, int out_size, void* d_ws, size_t ws_size,
                              hipStream_t stream) {
    const float* x   = (const float*)d_in[0];
    const int*   ei  = (const int*)d_in[1];
    const float* W1  = (const float*)d_in[2];
    const float* a1s = (const float*)d_in[3];
    const float* a1d = (const float*)d_in[4];
    const float* b1  = (const float*)d_in[5];
    const float* W2  = (const float*)d_in[6];
    const float* a2s = (const float*)d_in[7];
    const float* a2d = (const float*)d_in[8];
    const float* b2  = (const float*)d_in[9];
    const float* W3  = (const float*)d_in[10];
    const float* a3s = (const float*)d_in[11];
    const float* a3d = (const float*)d_in[12];
    const float* b3  = (const float*)d_in[13];
    float* out = (float*)d_out;

    // workspace layout (~105 MB)
    char* w = (char*)d_ws;
    unsigned char* hbuf8 = (unsigned char*)w;                  // NP*448 fp8 (22.5 MB); layer-3 reuses as bf16 NP*32
    __hip_bfloat16* hbuf3 = (__hip_bfloat16*)w;
    ushort* xb = (ushort*)(w + (size_t)NP * 448);              // NP*256 bf16 (25.7 MB)
    __hip_bfloat16* act = (__hip_bfloat16*)(xb + (size_t)NP * 256);  // NP*448 bf16 (44.9 MB)
    float* as8 = (float*)(act + (size_t)NP * 448);             // N*8 f32
    float* ad8 = as8 + (size_t)NN * 8;                         // N*8 f32
    int* cnt     = (int*)(ad8 + (size_t)NN * 8);               // N
    int* fillc   = cnt + NN;                                   // N
    int* row_ptr = fillc + NN;                                 // N+4 (padded)
    int* tmp     = row_ptr + (NN + 4);                         // N
    int* part    = tmp + NN;                                   // 256
    int* colA    = part + 256;                                 // ET
    char* pw = (char*)(colA + ET);
    pw = (char*)(((uintptr_t)pw + 15) & ~(uintptr_t)15);
    ushort* Wt1 = (ushort*)pw;                                 // 448*256
    ushort* Wt2 = Wt1 + 448 * 256;                             // 448*448
    ushort* Wt3 = Wt2 + 448 * 448;                             // 64*448 (rows 32..63 poison, never stored)

    hipMemsetAsync(cnt, 0, 2 * (size_t)NN * sizeof(int), stream);  // cnt + fillc

    // fused prep (wt x3 + x->bf16) + CSR count
    gat_prepcnt_kernel<<<PBLK + CBLK, 256, 0, stream>>>(W1, W2, W3, x, Wt1, Wt2, Wt3, xb, ei, cnt);
    gat_scan1_kernel<<<NB_SCAN, 256, 0, stream>>>(cnt, tmp, part);
    gat_scan2_kernel<<<1, 256, 0, stream>>>(part);
    gat_scan3_kernel<<<NB_SCAN, 256, 0, stream>>>(tmp, part, row_ptr);
    gat_fill_kernel<<<CBLK, 256, 0, stream>>>(ei, row_ptr, fillc, colA);

    dim3 gemmBlk(256);
    int mtilesF = NP / 64;              // 784 (fused-head GEMM, layers 1&2; also layer-3 RF=1)
    int aggBlocks = (NN + 3) / 4;       // 12500

    // --- layer 1 (fused heads; alpha fused; h written as fp8)
    gat_gemmF_kernel<<<mtilesF, gemmBlk, 0, stream>>>(
        xb, Wt1, hbuf8, a1s, a1d, as8, ad8, 256);
    gat_aggC7_kernel<<<aggBlocks, 256, 0, stream>>>(row_ptr, colA, as8, ad8, hbuf8, b1, act);

    // --- layer 2
    gat_gemmF_kernel<<<mtilesF, gemmBlk, 0, stream>>>(
        (const ushort*)act, Wt2, hbuf8, a2s, a2d, as8, ad8, 448);
    gat_aggC7_kernel<<<aggBlocks, 256, 0, stream>>>(row_ptr, colA, as8, ad8, hbuf8, b2, act);

    // --- layer 3 (1 head, 32 ch, alpha fused, bf16 h, RF=1 for occupancy, log_softmax, fp32 out)
    gat_gemm_kernel<1, 2, 0><<<dim3(mtilesF, 1), gemmBlk, 0, stream>>>(
        (const ushort*)act, Wt3, hbuf3, a3s, a3d, as8, ad8, NN, 448, 32);
    int fBlocks = (NN + 7) / 8;  // 8 dsts per block (2 per wave)
    gat_aggCF_kernel<<<fBlocks, 256, 0, stream>>>(row_ptr, colA, as8, ad8, hbuf3, b3, out);
}

// Round 11
// 467.623 us; speedup vs baseline: 1.1006x; 1.0939x over previous
//
#include <hip/hip_runtime.h>
#include <hip/hip_bf16.h>
#include <hip/hip_fp16.h>

#define NN 50000
#define NP 50176              // NN padded to multiple of 256 (GEMM tiles, no bounds checks)
#define EE 800000
#define ET (EE + NN)          // 850000 edges incl self-loops
#define NB_SCAN ((NN + 255) / 256)   // 196

typedef __attribute__((ext_vector_type(8))) short bf16x8;
typedef __attribute__((ext_vector_type(4))) float f32x4;
typedef __attribute__((ext_vector_type(2))) float f32x2;
typedef __attribute__((ext_vector_type(4))) unsigned int u32x4;

static __device__ __forceinline__ float bf2f(__hip_bfloat16 x) { return __bfloat162float(x); }
static __device__ __forceinline__ ushort f2bu(float f) {
    union { __hip_bfloat16 b; ushort u; } c;
    c.b = __float2bfloat16(f);
    return c.u;
}
static __device__ __forceinline__ float u2f(ushort u) {
    union { ushort u; __hip_bfloat16 b; } c;
    c.u = u;
    return __bfloat162float(c.b);
}
// fp8 e4m3 HW conversion (gfx950). Encode+decode use the same HW format -> self-consistent.
static __device__ __forceinline__ unsigned char f2fp8(float v) {
    int p = __builtin_amdgcn_cvt_pk_fp8_f32(v, v, 0, false);
    return (unsigned char)(p & 0xff);
}
// decode 4 packed fp8 bytes -> two f32 pairs, packed-FMA (v_pk_fma_f32) into two f32x2 accumulators.
static __device__ __forceinline__ void fp8acc_pk(unsigned v, f32x2 w2, f32x2& a01, f32x2& a23) {
#if __has_builtin(__builtin_amdgcn_cvt_pk_f32_fp8)
    f32x2 f01 = __builtin_amdgcn_cvt_pk_f32_fp8((int)v, false);
    f32x2 f23 = __builtin_amdgcn_cvt_pk_f32_fp8((int)v, true);
#else
    f32x2 f01 = { __builtin_amdgcn_cvt_f32_fp8(v, 0), __builtin_amdgcn_cvt_f32_fp8(v, 1) };
    f32x2 f23 = { __builtin_amdgcn_cvt_f32_fp8(v, 2), __builtin_amdgcn_cvt_f32_fp8(v, 3) };
#endif
    asm("v_pk_fma_f32 %0, %1, %2, %0" : "+v"(a01) : "v"(f01), "v"(w2));
    asm("v_pk_fma_f32 %0, %1, %2, %0" : "+v"(a23) : "v"(f23), "v"(w2));
}
// async global->LDS DMA, 16B per lane; lds dest must be wave-uniform base
static __device__ __forceinline__ void gl2lds(const ushort* g, ushort* l) {
    __builtin_amdgcn_global_load_lds(
        (const __attribute__((address_space(1))) void*)g,
        (__attribute__((address_space(3))) void*)l,
        16, 0, 0);
}

// ---------------------------------------------------------------- fused prep + CSR count
#define PA1 (256 * 448)
#define PA2 (448 * 448)
#define PA3 (448 * 32)
#define PXQ (NN * 64)   // x quads (256 ch / 4)
#define PTOT (PA1 + PA2 + PA3 + PXQ)
#define PBLK ((PTOT + 255) / 256)
#define CBLK ((ET + 255) / 256)

__global__ void gat_prepcnt_kernel(const float* __restrict__ W1, const float* __restrict__ W2,
                                   const float* __restrict__ W3, const float* __restrict__ x,
                                   ushort* __restrict__ Wt1, ushort* __restrict__ Wt2,
                                   ushort* __restrict__ Wt3, ushort* __restrict__ xb,
                                   const int* __restrict__ ei, int* __restrict__ cnt) {
    int b = blockIdx.x;
    if (b >= PBLK) {
        int i = (b - PBLK) * 256 + threadIdx.x;
        if (i < ET) {
            int dst = (i < EE) ? ei[EE + i] : (i - EE);
            atomicAdd(&cnt[dst], 1);
        }
        return;
    }
    int i = b * 256 + threadIdx.x;
    if (i < PA1) {
        int k = i / 448, n = i - k * 448;
        Wt1[(size_t)n * 256 + k] = f2bu(W1[i]);
        return;
    }
    i -= PA1;
    if (i < PA2) {
        int k = i / 448, n = i - k * 448;
        Wt2[(size_t)n * 448 + k] = f2bu(W2[i]);
        return;
    }
    i -= PA2;
    if (i < PA3) {
        int k = i / 32, n = i - k * 32;
        Wt3[(size_t)n * 448 + k] = f2bu(W3[i]);
        return;
    }
    i -= PA3;
    if (i < PXQ) {
        float4 f = ((const float4*)x)[i];
        ushort u[4] = {f2bu(f.x), f2bu(f.y), f2bu(f.z), f2bu(f.w)};
        ((uint2*)xb)[i] = *(const uint2*)u;
    }
}

// ---------------------------------------------------------------- CSR scans + fill
__global__ void gat_scan1_kernel(const int* __restrict__ cnt, int* __restrict__ tmp,
                                 int* __restrict__ part) {
    __shared__ int sm[256];
    int tid = threadIdx.x;
    int i = blockIdx.x * 256 + tid;
    int v = (i < NN) ? cnt[i] : 0;
    sm[tid] = v;
    __syncthreads();
    for (int o = 1; o < 256; o <<= 1) {
        int t = (tid >= o) ? sm[tid - o] : 0;
        __syncthreads();
        sm[tid] += t;
        __syncthreads();
    }
    if (i < NN) tmp[i] = sm[tid];
    if (tid == 255) part[blockIdx.x] = sm[255];
}

__global__ void gat_scan2_kernel(int* __restrict__ part) {
    __shared__ int sm[256];
    int tid = threadIdx.x;
    int v = (tid < NB_SCAN) ? part[tid] : 0;
    sm[tid] = v;
    __syncthreads();
    for (int o = 1; o < 256; o <<= 1) {
        int t = (tid >= o) ? sm[tid - o] : 0;
        __syncthreads();
        sm[tid] += t;
        __syncthreads();
    }
    part[tid] = sm[tid];
}

__global__ void gat_scan3_kernel(const int* __restrict__ tmp, const int* __restrict__ part,
                                 int* __restrict__ row_ptr) {
    int i = blockIdx.x * 256 + threadIdx.x;
    int off = (blockIdx.x > 0) ? part[blockIdx.x - 1] : 0;
    if (i < NN) row_ptr[i + 1] = tmp[i] + off;
    if (i == 0) row_ptr[0] = 0;
}

__global__ void gat_fill_kernel(const int* __restrict__ ei, const int* __restrict__ row_ptr,
                                int* __restrict__ fillc, int* __restrict__ colA) {
    int i = blockIdx.x * blockDim.x + threadIdx.x;
    if (i >= ET) return;
    int s, d;
    if (i < EE) { s = ei[i]; d = ei[EE + i]; }
    else        { s = d = i - EE; }
    int pos = row_ptr[d] + atomicAdd(&fillc[d], 1);
    colA[pos] = s;
}

// ---------------------------------------------------------------- GEMM core (bf16 A, DMA staging, LDS dbuf)
// C[M,N] = A[M,K] * W[K,N]; W pre-transposed bf16 Wt[N][K]. A padded to NP rows.
// RF = 16-row frags per wave (BM = RF*64).
// DOA=1: fuse 64-ch alpha; XCD-aware flat blockIdx co-schedules all 7 heads of an m-tile
//        on one XCD (ids differing by 8 share an XCD) -> A-tile L2-shared across heads.
// DOA=2: 32-ch alpha. OM=1: C fp8 e4m3.
// LDS chunk-swizzle (T2, rule #21; mechanism verified R10: conflicts 5.09M->0, bit-identical):
// stage global chunk (l&3)^((l>>3)&3) into linear LDS -> LDS[r][c]=G[r][c^((r>>1)&3)];
// fragment read uses chunk lq^((lrow>>1)&3) -> G[lrow][lq]. Kills the stride-64B
// 16-lane ds_read_b128 aliasing ((4r+lq)&7 hits only {lq,lq+4} -> ~8 lanes/16B-group).
#define GBN 64
#define GBK 32

template <int RF, int DOA, int OM>
__global__ __launch_bounds__(256) void gat_gemm_kernel(
    const ushort* __restrict__ A, const ushort* __restrict__ Wt,
    void* __restrict__ Cv,
    const float* __restrict__ Asrc, const float* __restrict__ Adst,
    float* __restrict__ as8, float* __restrict__ ad8,
    int M, int K, int N) {
    constexpr int GBM = RF * 64;
    constexpr int MT = NP / GBM;        // total m-tiles
    __shared__ __align__(16) ushort As[2][GBM * GBK];
    __shared__ __align__(16) ushort Bs[2][GBN * GBK];
    int tid = threadIdx.x;
    int wave = tid >> 6, lane = tid & 63;
    int lrow = lane & 15, lq = lane >> 4;

    int mt, head;
    if constexpr (DOA == 1) {
        int id = blockIdx.x;
        int xcd = id & 7, r = id >> 3;
        int g = r / 7;
        head = r - g * 7;
        mt = xcd + g * 8;               // same-m-tile heads: ids differ by 8 -> same XCD
        if (mt >= MT) return;
    } else {
        mt = blockIdx.x;
        head = blockIdx.y;
    }
    int m0 = mt * GBM, n0 = head * GBN;

    int srow = lane >> 2;
    int schunk = ((lane & 3) ^ ((lane >> 3) & 3)) * 8;  // inverse-swizzled global chunk
    int swz = (lrow >> 1) & 3;                          // read-side swizzle
    f32x4 acc[RF][4] = {};

    int KT = K / GBK;
    {
#pragma unroll
        for (int q = 0; q < RF; q++) {
            const ushort* gp = A + (size_t)(m0 + wave * RF * 16 + q * 16 + srow) * K + schunk;
            gl2lds(gp, &As[0][(wave * RF * 16 + q * 16) * GBK]);
        }
        const ushort* gb = Wt + (size_t)(n0 + wave * 16 + srow) * K + schunk;
        gl2lds(gb, &Bs[0][wave * 16 * GBK]);
    }
    for (int kt = 0; kt < KT; kt++) {
        __syncthreads();
        if (kt + 1 < KT) {
            int nb = (kt + 1) & 1, k0 = (kt + 1) * GBK;
#pragma unroll
            for (int q = 0; q < RF; q++) {
                const ushort* gp = A + (size_t)(m0 + wave * RF * 16 + q * 16 + srow) * K + k0 + schunk;
                gl2lds(gp, &As[nb][(wave * RF * 16 + q * 16) * GBK]);
            }
            const ushort* gb = Wt + (size_t)(n0 + wave * 16 + srow) * K + k0 + schunk;
            gl2lds(gb, &Bs[nb][wave * 16 * GBK]);
        }
        int b = kt & 1;
        bf16x8 af[RF];
#pragma unroll
        for (int rf = 0; rf < RF; rf++)
            af[rf] = *(const bf16x8*)&As[b][(wave * RF * 16 + rf * 16 + lrow) * GBK + (lq ^ swz) * 8];
#pragma unroll
        for (int ng = 0; ng < 4; ng++) {
            bf16x8 bf = *(const bf16x8*)&Bs[b][(ng * 16 + lrow) * GBK + (lq ^ swz) * 8];
#pragma unroll
            for (int rf = 0; rf < RF; rf++)
                acc[rf][ng] = __builtin_amdgcn_mfma_f32_16x16x32_bf16(af[rf], bf, acc[rf][ng], 0, 0, 0);
        }
    }
    // epilogue: C/D layout col=lane&15 (within ng group), row=lq*4+r
#pragma unroll
    for (int rf = 0; rf < RF; rf++)
#pragma unroll
        for (int ng = 0; ng < 4; ng++)
#pragma unroll
            for (int r = 0; r < 4; r++) {
                int row = m0 + wave * RF * 16 + rf * 16 + lq * 4 + r;
                int colI = n0 + ng * 16 + lrow;
                if (row < M && colI < N) {
                    if constexpr (OM == 0)
                        ((__hip_bfloat16*)Cv)[(size_t)row * N + colI] = __float2bfloat16(acc[rf][ng][r]);
                    else
                        ((unsigned char*)Cv)[(size_t)row * N + colI] = f2fp8(acc[rf][ng][r]);
                }
            }
    if constexpr (DOA == 1) {
        float as_l[4], ad_l[4];
#pragma unroll
        for (int ng = 0; ng < 4; ng++) {
            as_l[ng] = Asrc[head * 64 + ng * 16 + lrow];
            ad_l[ng] = Adst[head * 64 + ng * 16 + lrow];
        }
#pragma unroll
        for (int rf = 0; rf < RF; rf++)
#pragma unroll
            for (int r = 0; r < 4; r++) {
                float ps = 0.f, pd = 0.f;
#pragma unroll
                for (int ng = 0; ng < 4; ng++) {
                    ps += acc[rf][ng][r] * as_l[ng];
                    pd += acc[rf][ng][r] * ad_l[ng];
                }
#pragma unroll
                for (int o = 1; o < 16; o <<= 1) {
                    ps += __shfl_xor(ps, o);
                    pd += __shfl_xor(pd, o);
                }
                int row = m0 + wave * RF * 16 + rf * 16 + lq * 4 + r;
                if (lrow == 0 && row < M) {
                    as8[(size_t)row * 8 + head] = ps;
                    ad8[(size_t)row * 8 + head] = pd;
                }
            }
    } else if constexpr (DOA == 2) {
        float as_l[2], ad_l[2];
#pragma unroll
        for (int ng = 0; ng < 2; ng++) {
            as_l[ng] = Asrc[ng * 16 + lrow];
            ad_l[ng] = Adst[ng * 16 + lrow];
        }
#pragma unroll
        for (int rf = 0; rf < RF; rf++)
#pragma unroll
            for (int r = 0; r < 4; r++) {
                float ps = acc[rf][0][r] * as_l[0] + acc[rf][1][r] * as_l[1];
                float pd = acc[rf][0][r] * ad_l[0] + acc[rf][1][r] * ad_l[1];
#pragma unroll
                for (int o = 1; o < 16; o <<= 1) {
                    ps += __shfl_xor(ps, o);
                    pd += __shfl_xor(pd, o);
                }
                int row = m0 + wave * RF * 16 + rf * 16 + lq * 4 + r;
                if (lrow == 0 && row < M) {
                    as8[(size_t)row * 8] = ps;
                    ad8[(size_t)row * 8] = pd;
                }
            }
    }
}

// ---------------------------------------------------------------- Phase C: wave-per-dst, fp8 h-table gather
// R7 version (66.9us, best measured): index preload + readlane -> zero dependent loads in
// inner loop; 2-deep gather pipeline; NT on streaming colA/out. At its memory-path floor
// (~211MB L2-miss traffic @ ~3.9TB/s); VALU/latency surgery is neutral-to-negative (R8).
__global__ void gat_aggC7_kernel(const int* __restrict__ rp, const int* __restrict__ colA,
                                 const float* __restrict__ as8, const float* __restrict__ ad8,
                                 const unsigned char* __restrict__ h8,
                                 const float* __restrict__ bias,
                                 __hip_bfloat16* __restrict__ outp) {
    int d = blockIdx.x * 4 + (threadIdx.x >> 6);
    if (d >= NN) return;
    int lane = threadIdx.x & 63;
    int lc = (lane < 56) ? lane : 55;           // clamp: lanes 56-63 duplicate lane 55
    unsigned hh = (unsigned)(lc >> 3);
    unsigned lb = (unsigned)lc * 8u;
    float adh = ad8[(size_t)d * 8 + hh];
    int s0 = rp[d], s1 = rp[d + 1];
    int s1m1 = s1 - 1;
    f32x2 a01 = {0.f, 0.f}, a23 = {0.f, 0.f}, a45 = {0.f, 0.f}, a67 = {0.f, 0.f};
    float den = 0.f;

#define GATHER4(B4, ASV, HV) do {                                      \
        _Pragma("unroll")                                              \
        for (int k_ = 0; k_ < 4; k_++) {                               \
            unsigned s_ = (unsigned)__builtin_amdgcn_readlane(myIdx, (B4) + k_); \
            ASV[k_] = as8[s_ * 8u + hh];                               \
            HV[k_] = *(const uint2*)(h8 + (s_ * 448u + lb));           \
        }                                                              \
    } while (0)

#define CONSUME(ASV, HV, JJ) do {                                      \
        float w_[4];                                                   \
        _Pragma("unroll")                                              \
        for (int k_ = 0; k_ < 4; k_++) {                               \
            float e_ = ASV[k_] + adh;                                  \
            e_ = (e_ > 0.f) ? e_ : 0.2f * e_;                          \
            float ww_ = __expf(e_);                                    \
            ww_ = ((JJ) + k_ < s1) ? ww_ : 0.f;                        \
            w_[k_] = ww_;                                              \
            den += ww_;                                                \
        }                                                              \
        _Pragma("unroll")                                              \
        for (int k_ = 0; k_ < 4; k_++) {                               \
            f32x2 w2_ = {w_[k_], w_[k_]};                              \
            fp8acc_pk(HV[k_].x, w2_, a01, a23);                        \
            fp8acc_pk(HV[k_].y, w2_, a45, a67);                        \
        }                                                              \
    } while (0)

    // chunked over 64-edge windows (deg > 64 essentially never occurs; loop is correctness armor)
    for (int base = s0; base < s1; base += 64) {
        int myIdx = __builtin_nontemporal_load(colA + (unsigned)min(base + lane, s1m1));
        int cnt = min(s1 - base, 64);
        int nb = (cnt + 3) >> 2;                              // >=1
        int jb = base;
        int b4 = 0;
        float as0v[4], as1v[4];
        uint2 hv0[4], hv1[4];
        GATHER4(0, as0v, hv0);
        int rem = nb - 1;
        while (rem >= 2) {
            GATHER4(b4 + 4, as1v, hv1); CONSUME(as0v, hv0, jb); jb += 4;
            GATHER4(b4 + 8, as0v, hv0); CONSUME(as1v, hv1, jb); jb += 4;
            b4 += 8; rem -= 2;
        }
        if (rem == 1) {
            GATHER4(b4 + 4, as1v, hv1); CONSUME(as0v, hv0, jb); jb += 4;
            CONSUME(as1v, hv1, jb);
        } else {
            CONSUME(as0v, hv0, jb);
        }
    }
#undef GATHER4
#undef CONSUME

    float inv = 1.f / (den + 1e-16f);
    const float4* bp = (const float4*)(bias + lb);
    float4 bb0 = bp[0], bb1 = bp[1];
    float bv[8] = {bb0.x, bb0.y, bb0.z, bb0.w, bb1.x, bb1.y, bb1.z, bb1.w};
    float av[8] = {a01.x, a01.y, a23.x, a23.y, a45.x, a45.y, a67.x, a67.y};
    ushort o8[8];
#pragma unroll
    for (int k = 0; k < 8; k++) {
        float o = av[k] * inv + bv[k];
        o = fmaxf(o, 0.f);
        o8[k] = f2bu(o);
    }
    if (lane < 56) {
        u32x4 ov = *(const u32x4*)o8;
        __builtin_nontemporal_store(ov, (u32x4*)((ushort*)outp + (size_t)d * 448 + lane * 8));
    }
}

// ---------------------------------------------------------------- Phase C final: 2 dsts/wave, 32 ch (bf16 h), log_softmax
// R4 version (no NT) to match the best-measured 463.9us configuration.
__global__ void gat_aggCF_kernel(const int* __restrict__ rp, const int* __restrict__ colA,
                                 const float* __restrict__ as8, const float* __restrict__ ad8,
                                 const __hip_bfloat16* __restrict__ h,
                                 const float* __restrict__ bias,
                                 float* __restrict__ outp) {
    int wid = blockIdx.x * 4 + (threadIdx.x >> 6);
    int lane = threadIdx.x & 63;
    int half = lane >> 5;
    unsigned c = (unsigned)(lane & 31);
    int dreal = wid * 2 + half;
    bool valid = dreal < NN;
    int d = valid ? dreal : (NN - 1);
    float adh = ad8[(size_t)d * 8];
    int s0 = rp[d], s1 = rp[d + 1];
    float acc = 0.f, den = 0.f;
    int j = s0;
    for (; j + 2 <= s1; j += 2) {
        unsigned ju = (unsigned)j;
        unsigned sA = (unsigned)colA[ju];
        unsigned sB = (unsigned)colA[ju + 1];
        float eA = as8[sA * 8u] + adh;
        float eB = as8[sB * 8u] + adh;
        float vA = bf2f(h[sA * 32u + c]);
        float vB = bf2f(h[sB * 32u + c]);
        eA = (eA > 0.f) ? eA : 0.2f * eA;
        eB = (eB > 0.f) ? eB : 0.2f * eB;
        float wA = __expf(eA), wB = __expf(eB);
        den += wA + wB;
        acc += wA * vA + wB * vB;
    }
    for (; j < s1; j++) {
        unsigned s = (unsigned)colA[(unsigned)j];
        float e = as8[s * 8u] + adh;
        e = (e > 0.f) ? e : 0.2f * e;
        float w = __expf(e);
        den += w;
        acc += w * bf2f(h[s * 32u + c]);
    }
    float o = acc / (den + 1e-16f) + bias[c];
    float t = o;
#pragma unroll
    for (int off = 16; off > 0; off >>= 1) t = fmaxf(t, __shfl_xor(t, off));
    float ex = __expf(o - t);
#pragma unroll
    for (int off = 16; off > 0; off >>= 1) ex += __shfl_xor(ex, off);
    float res = o - t - __logf(ex);
    if (valid) outp[(size_t)d * 32 + c] = res;
}

// ---------------------------------------------------------------- launch
extern "C" void kernel_launch(void* const* d_in, const int* in_sizes, int n_in,
                              void* d_out, int out_size, void* d_ws, size_t ws_size,
                              hipStream_t stream) {
    const float* x   = (const float*)d_in[0];
    const int*   ei  = (const int*)d_in[1];
    const float* W1  = (const float*)d_in[2];
    const float* a1s = (const float*)d_in[3];
    const float* a1d = (const float*)d_in[4];
    const float* b1  = (const float*)d_in[5];
    const float* W2  = (const float*)d_in[6];
    const float* a2s = (const float*)d_in[7];
    const float* a2d = (const float*)d_in[8];
    const float* b2  = (const float*)d_in[9];
    const float* W3  = (const float*)d_in[10];
    const float* a3s = (const float*)d_in[11];
    const float* a3d = (const float*)d_in[12];
    const float* b3  = (const float*)d_in[13];
    float* out = (float*)d_out;

    // workspace layout (~105 MB)
    char* w = (char*)d_ws;
    unsigned char* hbuf8 = (unsigned char*)w;                  // NP*448 fp8 (22.5 MB); layer-3 reuses as bf16 NP*32
    __hip_bfloat16* hbuf3 = (__hip_bfloat16*)w;
    ushort* xb = (ushort*)(w + (size_t)NP * 448);              // NP*256 bf16 (25.7 MB)
    __hip_bfloat16* act = (__hip_bfloat16*)(xb + (size_t)NP * 256);  // NP*448 bf16 (44.9 MB)
    float* as8 = (float*)(act + (size_t)NP * 448);             // N*8 f32
    float* ad8 = as8 + (size_t)NN * 8;                         // N*8 f32
    int* cnt     = (int*)(ad8 + (size_t)NN * 8);               // N
    int* fillc   = cnt + NN;                                   // N
    int* row_ptr = fillc + NN;                                 // N+4 (padded)
    int* tmp     = row_ptr + (NN + 4);                         // N
    int* part    = tmp + NN;                                   // 256
    int* colA    = part + 256;                                 // ET
    char* pw = (char*)(colA + ET);
    pw = (char*)(((uintptr_t)pw + 15) & ~(uintptr_t)15);
    ushort* Wt1 = (ushort*)pw;                                 // 448*256
    ushort* Wt2 = Wt1 + 448 * 256;                             // 448*448
    ushort* Wt3 = Wt2 + 448 * 448;                             // 64*448 (rows 32..63 poison, never stored)

    hipMemsetAsync(cnt, 0, 2 * (size_t)NN * sizeof(int), stream);  // cnt + fillc

    // fused prep (wt x3 + x->bf16) + CSR count
    gat_prepcnt_kernel<<<PBLK + CBLK, 256, 0, stream>>>(W1, W2, W3, x, Wt1, Wt2, Wt3, xb, ei, cnt);
    gat_scan1_kernel<<<NB_SCAN, 256, 0, stream>>>(cnt, tmp, part);
    gat_scan2_kernel<<<1, 256, 0, stream>>>(part);
    gat_scan3_kernel<<<NB_SCAN, 256, 0, stream>>>(tmp, part, row_ptr);
    gat_fill_kernel<<<CBLK, 256, 0, stream>>>(ei, row_ptr, fillc, colA);

    dim3 gemmBlk(256);
    // XCD-aware head-fused grid for DOA=1 GEMMs: 8 xcd-slots x ceil(196/8) groups x 7 heads
    int swzBlocks = 8 * ((196 + 7) / 8) * 7;   // 1400 (blocks with mt>=196 exit early)
    int mtiles1 = NP / 64;              // 784 (RF=1, layer 3)
    int aggBlocks = (NN + 3) / 4;       // 12500

    // --- layer 1 (alpha fused; h written as fp8)
    gat_gemm_kernel<4, 1, 1><<<swzBlocks, gemmBlk, 0, stream>>>(
        xb, Wt1, hbuf8, a1s, a1d, as8, ad8, NN, 256, 448);
    gat_aggC7_kernel<<<aggBlocks, 256, 0, stream>>>(row_ptr, colA, as8, ad8, hbuf8, b1, act);

    // --- layer 2
    gat_gemm_kernel<4, 1, 1><<<swzBlocks, gemmBlk, 0, stream>>>(
        (const ushort*)act, Wt2, hbuf8, a2s, a2d, as8, ad8, NN, 448, 448);
    gat_aggC7_kernel<<<aggBlocks, 256, 0, stream>>>(row_ptr, colA, as8, ad8, hbuf8, b2, act);

    // --- layer 3 (1 head, 32 ch, alpha fused, bf16 h, RF=1 for occupancy, log_softmax, fp32 out)
    gat_gemm_kernel<1, 2, 0><<<dim3(mtiles1, 1), gemmBlk, 0, stream>>>(
        (const ushort*)act, Wt3, hbuf3, a3s, a3d, as8, ad8, NN, 448, 32);
    int fBlocks = (NN + 7) / 8;  // 8 dsts per block (2 per wave)
    gat_aggCF_kernel<<<fBlocks, 256, 0, stream>>>(row_ptr, colA, as8, ad8, hbuf3, b3, out);
}

// Round 12
// 463.793 us; speedup vs baseline: 1.1097x; 1.0083x over previous
//
#include <hip/hip_runtime.h>
#include <hip/hip_bf16.h>
#include <hip/hip_fp16.h>

#define NN 50000
#define NP 50176              // NN padded to multiple of 256 (GEMM tiles, no bounds checks)
#define EE 800000
#define ET (EE + NN)          // 850000 edges incl self-loops
#define NB_SCAN ((NN + 255) / 256)   // 196

typedef __attribute__((ext_vector_type(8))) short bf16x8;
typedef __attribute__((ext_vector_type(4))) float f32x4;
typedef __attribute__((ext_vector_type(2))) float f32x2;
typedef __attribute__((ext_vector_type(4))) unsigned int u32x4;

static __device__ __forceinline__ float bf2f(__hip_bfloat16 x) { return __bfloat162float(x); }
static __device__ __forceinline__ ushort f2bu(float f) {
    union { __hip_bfloat16 b; ushort u; } c;
    c.b = __float2bfloat16(f);
    return c.u;
}
static __device__ __forceinline__ float u2f(ushort u) {
    union { ushort u; __hip_bfloat16 b; } c;
    c.u = u;
    return __bfloat162float(c.b);
}
// fp8 e4m3 HW conversion (gfx950). Encode+decode use the same HW format -> self-consistent.
static __device__ __forceinline__ unsigned char f2fp8(float v) {
    int p = __builtin_amdgcn_cvt_pk_fp8_f32(v, v, 0, false);
    return (unsigned char)(p & 0xff);
}
// decode 4 packed fp8 bytes -> two f32 pairs, packed-FMA (v_pk_fma_f32) into two f32x2 accumulators.
static __device__ __forceinline__ void fp8acc_pk(unsigned v, f32x2 w2, f32x2& a01, f32x2& a23) {
#if __has_builtin(__builtin_amdgcn_cvt_pk_f32_fp8)
    f32x2 f01 = __builtin_amdgcn_cvt_pk_f32_fp8((int)v, false);
    f32x2 f23 = __builtin_amdgcn_cvt_pk_f32_fp8((int)v, true);
#else
    f32x2 f01 = { __builtin_amdgcn_cvt_f32_fp8(v, 0), __builtin_amdgcn_cvt_f32_fp8(v, 1) };
    f32x2 f23 = { __builtin_amdgcn_cvt_f32_fp8(v, 2), __builtin_amdgcn_cvt_f32_fp8(v, 3) };
#endif
    asm("v_pk_fma_f32 %0, %1, %2, %0" : "+v"(a01) : "v"(f01), "v"(w2));
    asm("v_pk_fma_f32 %0, %1, %2, %0" : "+v"(a23) : "v"(f23), "v"(w2));
}
// async global->LDS DMA, 16B per lane; lds dest must be wave-uniform base
static __device__ __forceinline__ void gl2lds(const ushort* g, ushort* l) {
    __builtin_amdgcn_global_load_lds(
        (const __attribute__((address_space(1))) void*)g,
        (__attribute__((address_space(3))) void*)l,
        16, 0, 0);
}

// ---------------------------------------------------------------- fused prep + CSR count
#define PA1 (256 * 448)
#define PA2 (448 * 448)
#define PA3 (448 * 32)
#define PXQ (NN * 64)   // x quads (256 ch / 4)
#define PTOT (PA1 + PA2 + PA3 + PXQ)
#define PBLK ((PTOT + 255) / 256)
#define CBLK ((ET + 255) / 256)

__global__ void gat_prepcnt_kernel(const float* __restrict__ W1, const float* __restrict__ W2,
                                   const float* __restrict__ W3, const float* __restrict__ x,
                                   ushort* __restrict__ Wt1, ushort* __restrict__ Wt2,
                                   ushort* __restrict__ Wt3, ushort* __restrict__ xb,
                                   const int* __restrict__ ei, int* __restrict__ cnt) {
    int b = blockIdx.x;
    if (b >= PBLK) {
        int i = (b - PBLK) * 256 + threadIdx.x;
        if (i < ET) {
            int dst = (i < EE) ? ei[EE + i] : (i - EE);
            atomicAdd(&cnt[dst], 1);
        }
        return;
    }
    int i = b * 256 + threadIdx.x;
    if (i < PA1) {
        int k = i / 448, n = i - k * 448;
        Wt1[(size_t)n * 256 + k] = f2bu(W1[i]);
        return;
    }
    i -= PA1;
    if (i < PA2) {
        int k = i / 448, n = i - k * 448;
        Wt2[(size_t)n * 448 + k] = f2bu(W2[i]);
        return;
    }
    i -= PA2;
    if (i < PA3) {
        int k = i / 32, n = i - k * 32;
        Wt3[(size_t)n * 448 + k] = f2bu(W3[i]);
        return;
    }
    i -= PA3;
    if (i < PXQ) {
        float4 f = ((const float4*)x)[i];
        ushort u[4] = {f2bu(f.x), f2bu(f.y), f2bu(f.z), f2bu(f.w)};
        ((uint2*)xb)[i] = *(const uint2*)u;
    }
}

// ---------------------------------------------------------------- CSR scans + fill
__global__ void gat_scan1_kernel(const int* __restrict__ cnt, int* __restrict__ tmp,
                                 int* __restrict__ part) {
    __shared__ int sm[256];
    int tid = threadIdx.x;
    int i = blockIdx.x * 256 + tid;
    int v = (i < NN) ? cnt[i] : 0;
    sm[tid] = v;
    __syncthreads();
    for (int o = 1; o < 256; o <<= 1) {
        int t = (tid >= o) ? sm[tid - o] : 0;
        __syncthreads();
        sm[tid] += t;
        __syncthreads();
    }
    if (i < NN) tmp[i] = sm[tid];
    if (tid == 255) part[blockIdx.x] = sm[255];
}

__global__ void gat_scan2_kernel(int* __restrict__ part) {
    __shared__ int sm[256];
    int tid = threadIdx.x;
    int v = (tid < NB_SCAN) ? part[tid] : 0;
    sm[tid] = v;
    __syncthreads();
    for (int o = 1; o < 256; o <<= 1) {
        int t = (tid >= o) ? sm[tid - o] : 0;
        __syncthreads();
        sm[tid] += t;
        __syncthreads();
    }
    part[tid] = sm[tid];
}

__global__ void gat_scan3_kernel(const int* __restrict__ tmp, const int* __restrict__ part,
                                 int* __restrict__ row_ptr) {
    int i = blockIdx.x * 256 + threadIdx.x;
    int off = (blockIdx.x > 0) ? part[blockIdx.x - 1] : 0;
    if (i < NN) row_ptr[i + 1] = tmp[i] + off;
    if (i == 0) row_ptr[0] = 0;
}

__global__ void gat_fill_kernel(const int* __restrict__ ei, const int* __restrict__ row_ptr,
                                int* __restrict__ fillc, int* __restrict__ colA) {
    int i = blockIdx.x * blockDim.x + threadIdx.x;
    if (i >= ET) return;
    int s, d;
    if (i < EE) { s = ei[i]; d = ei[EE + i]; }
    else        { s = d = i - EE; }
    int pos = row_ptr[d] + atomicAdd(&fillc[d], 1);
    colA[pos] = s;
}

// ---------------------------------------------------------------- GEMM core (bf16 A, DMA staging, LDS dbuf)
// C[M,N] = A[M,K] * W[K,N]; W pre-transposed bf16 Wt[N][K]. A padded to NP rows.
// RF = 16-row frags per wave (BM = RF*64). NG = 16-col groups used (NG*16 <= GBN);
// NG=2 for layer 3 (N=32): skips the poison-B MFMAs and half the B staging (dead work).
// DOA=1: fuse 64-ch alpha; XCD-aware flat blockIdx co-schedules all 7 heads of an m-tile
//        on one XCD. DOA=2: 32-ch alpha. OM=1: C fp8 e4m3.
// LDS chunk-swizzle (T2, rule #21; verified R10: conflicts 5.09M->0, bit-identical).
#define GBN 64
#define GBK 32

template <int RF, int DOA, int OM, int NG>
__global__ __launch_bounds__(256) void gat_gemm_kernel(
    const ushort* __restrict__ A, const ushort* __restrict__ Wt,
    void* __restrict__ Cv,
    const float* __restrict__ Asrc, const float* __restrict__ Adst,
    float* __restrict__ as8, float* __restrict__ ad8,
    int M, int K, int N) {
    constexpr int GBM = RF * 64;
    constexpr int MT = NP / GBM;        // total m-tiles
    __shared__ __align__(16) ushort As[2][GBM * GBK];
    __shared__ __align__(16) ushort Bs[2][GBN * GBK];
    int tid = threadIdx.x;
    int wave = tid >> 6, lane = tid & 63;
    int lrow = lane & 15, lq = lane >> 4;

    int mt, head;
    if constexpr (DOA == 1) {
        int id = blockIdx.x;
        int xcd = id & 7, r = id >> 3;
        int g = r / 7;
        head = r - g * 7;
        mt = xcd + g * 8;               // same-m-tile heads: ids differ by 8 -> same XCD
        if (mt >= MT) return;
    } else {
        mt = blockIdx.x;
        head = blockIdx.y;
    }
    int m0 = mt * GBM, n0 = head * GBN;

    int srow = lane >> 2;
    int schunk = ((lane & 3) ^ ((lane >> 3) & 3)) * 8;  // inverse-swizzled global chunk
    int swz = (lrow >> 1) & 3;                          // read-side swizzle
    f32x4 acc[RF][NG] = {};

    int KT = K / GBK;
    {
#pragma unroll
        for (int q = 0; q < RF; q++) {
            const ushort* gp = A + (size_t)(m0 + wave * RF * 16 + q * 16 + srow) * K + schunk;
            gl2lds(gp, &As[0][(wave * RF * 16 + q * 16) * GBK]);
        }
        if (wave < NG) {
            const ushort* gb = Wt + (size_t)(n0 + wave * 16 + srow) * K + schunk;
            gl2lds(gb, &Bs[0][wave * 16 * GBK]);
        }
    }
    for (int kt = 0; kt < KT; kt++) {
        __syncthreads();
        if (kt + 1 < KT) {
            int nb = (kt + 1) & 1, k0 = (kt + 1) * GBK;
#pragma unroll
            for (int q = 0; q < RF; q++) {
                const ushort* gp = A + (size_t)(m0 + wave * RF * 16 + q * 16 + srow) * K + k0 + schunk;
                gl2lds(gp, &As[nb][(wave * RF * 16 + q * 16) * GBK]);
            }
            if (wave < NG) {
                const ushort* gb = Wt + (size_t)(n0 + wave * 16 + srow) * K + k0 + schunk;
                gl2lds(gb, &Bs[nb][wave * 16 * GBK]);
            }
        }
        int b = kt & 1;
        bf16x8 af[RF];
#pragma unroll
        for (int rf = 0; rf < RF; rf++)
            af[rf] = *(const bf16x8*)&As[b][(wave * RF * 16 + rf * 16 + lrow) * GBK + (lq ^ swz) * 8];
#pragma unroll
        for (int ng = 0; ng < NG; ng++) {
            bf16x8 bf = *(const bf16x8*)&Bs[b][(ng * 16 + lrow) * GBK + (lq ^ swz) * 8];
#pragma unroll
            for (int rf = 0; rf < RF; rf++)
                acc[rf][ng] = __builtin_amdgcn_mfma_f32_16x16x32_bf16(af[rf], bf, acc[rf][ng], 0, 0, 0);
        }
    }
    // epilogue: C/D layout col=lane&15 (within ng group), row=lq*4+r
#pragma unroll
    for (int rf = 0; rf < RF; rf++)
#pragma unroll
        for (int ng = 0; ng < NG; ng++)
#pragma unroll
            for (int r = 0; r < 4; r++) {
                int row = m0 + wave * RF * 16 + rf * 16 + lq * 4 + r;
                int colI = n0 + ng * 16 + lrow;
                if (row < M && colI < N) {
                    if constexpr (OM == 0)
                        ((__hip_bfloat16*)Cv)[(size_t)row * N + colI] = __float2bfloat16(acc[rf][ng][r]);
                    else
                        ((unsigned char*)Cv)[(size_t)row * N + colI] = f2fp8(acc[rf][ng][r]);
                }
            }
    if constexpr (DOA == 1) {
        float as_l[NG], ad_l[NG];
#pragma unroll
        for (int ng = 0; ng < NG; ng++) {
            as_l[ng] = Asrc[head * 64 + ng * 16 + lrow];
            ad_l[ng] = Adst[head * 64 + ng * 16 + lrow];
        }
#pragma unroll
        for (int rf = 0; rf < RF; rf++)
#pragma unroll
            for (int r = 0; r < 4; r++) {
                float ps = 0.f, pd = 0.f;
#pragma unroll
                for (int ng = 0; ng < NG; ng++) {
                    ps += acc[rf][ng][r] * as_l[ng];
                    pd += acc[rf][ng][r] * ad_l[ng];
                }
#pragma unroll
                for (int o = 1; o < 16; o <<= 1) {
                    ps += __shfl_xor(ps, o);
                    pd += __shfl_xor(pd, o);
                }
                int row = m0 + wave * RF * 16 + rf * 16 + lq * 4 + r;
                if (lrow == 0 && row < M) {
                    as8[(size_t)row * 8 + head] = ps;
                    ad8[(size_t)row * 8 + head] = pd;
                }
            }
    } else if constexpr (DOA == 2) {
        float as_l[2], ad_l[2];
#pragma unroll
        for (int ng = 0; ng < 2; ng++) {
            as_l[ng] = Asrc[ng * 16 + lrow];
            ad_l[ng] = Adst[ng * 16 + lrow];
        }
#pragma unroll
        for (int rf = 0; rf < RF; rf++)
#pragma unroll
            for (int r = 0; r < 4; r++) {
                float ps = acc[rf][0][r] * as_l[0] + acc[rf][1][r] * as_l[1];
                float pd = acc[rf][0][r] * ad_l[0] + acc[rf][1][r] * ad_l[1];
#pragma unroll
                for (int o = 1; o < 16; o <<= 1) {
                    ps += __shfl_xor(ps, o);
                    pd += __shfl_xor(pd, o);
                }
                int row = m0 + wave * RF * 16 + rf * 16 + lq * 4 + r;
                if (lrow == 0 && row < M) {
                    as8[(size_t)row * 8] = ps;
                    ad8[(size_t)row * 8] = pd;
                }
            }
    }
}

// ---------------------------------------------------------------- Phase C: wave-per-dst, fp8 h-table gather
// R7 version (66.9us, best measured): index preload + readlane -> zero dependent loads in
// inner loop; 2-deep gather pipeline; NT on streaming colA/out. At its memory-path floor
// (~211MB L2-miss traffic @ ~3.9TB/s); VALU/latency surgery is neutral-to-negative (R8).
__global__ void gat_aggC7_kernel(const int* __restrict__ rp, const int* __restrict__ colA,
                                 const float* __restrict__ as8, const float* __restrict__ ad8,
                                 const unsigned char* __restrict__ h8,
                                 const float* __restrict__ bias,
                                 __hip_bfloat16* __restrict__ outp) {
    int d = blockIdx.x * 4 + (threadIdx.x >> 6);
    if (d >= NN) return;
    int lane = threadIdx.x & 63;
    int lc = (lane < 56) ? lane : 55;           // clamp: lanes 56-63 duplicate lane 55
    unsigned hh = (unsigned)(lc >> 3);
    unsigned lb = (unsigned)lc * 8u;
    float adh = ad8[(size_t)d * 8 + hh];
    int s0 = rp[d], s1 = rp[d + 1];
    int s1m1 = s1 - 1;
    f32x2 a01 = {0.f, 0.f}, a23 = {0.f, 0.f}, a45 = {0.f, 0.f}, a67 = {0.f, 0.f};
    float den = 0.f;

#define GATHER4(B4, ASV, HV) do {                                      \
        _Pragma("unroll")                                              \
        for (int k_ = 0; k_ < 4; k_++) {                               \
            unsigned s_ = (unsigned)__builtin_amdgcn_readlane(myIdx, (B4) + k_); \
            ASV[k_] = as8[s_ * 8u + hh];                               \
            HV[k_] = *(const uint2*)(h8 + (s_ * 448u + lb));           \
        }                                                              \
    } while (0)

#define CONSUME(ASV, HV, JJ) do {                                      \
        float w_[4];                                                   \
        _Pragma("unroll")                                              \
        for (int k_ = 0; k_ < 4; k_++) {                               \
            float e_ = ASV[k_] + adh;                                  \
            e_ = (e_ > 0.f) ? e_ : 0.2f * e_;                          \
            float ww_ = __expf(e_);                                    \
            ww_ = ((JJ) + k_ < s1) ? ww_ : 0.f;                        \
            w_[k_] = ww_;                                              \
            den += ww_;                                                \
        }                                                              \
        _Pragma("unroll")                                              \
        for (int k_ = 0; k_ < 4; k_++) {                               \
            f32x2 w2_ = {w_[k_], w_[k_]};                              \
            fp8acc_pk(HV[k_].x, w2_, a01, a23);                        \
            fp8acc_pk(HV[k_].y, w2_, a45, a67);                        \
        }                                                              \
    } while (0)

    // chunked over 64-edge windows (deg > 64 essentially never occurs; loop is correctness armor)
    for (int base = s0; base < s1; base += 64) {
        int myIdx = __builtin_nontemporal_load(colA + (unsigned)min(base + lane, s1m1));
        int cnt = min(s1 - base, 64);
        int nb = (cnt + 3) >> 2;                              // >=1
        int jb = base;
        int b4 = 0;
        float as0v[4], as1v[4];
        uint2 hv0[4], hv1[4];
        GATHER4(0, as0v, hv0);
        int rem = nb - 1;
        while (rem >= 2) {
            GATHER4(b4 + 4, as1v, hv1); CONSUME(as0v, hv0, jb); jb += 4;
            GATHER4(b4 + 8, as0v, hv0); CONSUME(as1v, hv1, jb); jb += 4;
            b4 += 8; rem -= 2;
        }
        if (rem == 1) {
            GATHER4(b4 + 4, as1v, hv1); CONSUME(as0v, hv0, jb); jb += 4;
            CONSUME(as1v, hv1, jb);
        } else {
            CONSUME(as0v, hv0, jb);
        }
    }
#undef GATHER4
#undef CONSUME

    float inv = 1.f / (den + 1e-16f);
    const float4* bp = (const float4*)(bias + lb);
    float4 bb0 = bp[0], bb1 = bp[1];
    float bv[8] = {bb0.x, bb0.y, bb0.z, bb0.w, bb1.x, bb1.y, bb1.z, bb1.w};
    float av[8] = {a01.x, a01.y, a23.x, a23.y, a45.x, a45.y, a67.x, a67.y};
    ushort o8[8];
#pragma unroll
    for (int k = 0; k < 8; k++) {
        float o = av[k] * inv + bv[k];
        o = fmaxf(o, 0.f);
        o8[k] = f2bu(o);
    }
    if (lane < 56) {
        u32x4 ov = *(const u32x4*)o8;
        __builtin_nontemporal_store(ov, (u32x4*)((ushort*)outp + (size_t)d * 448 + lane * 8));
    }
}

// ---------------------------------------------------------------- Phase C final: 2 dsts/wave, 32 ch (bf16 h), log_softmax
// Index preload (half-wave lane c holds colA[s0+c]) + 2-deep pair pipeline, mirroring
// aggC7's proven structure: inner loop has no dependent colA->gather chain. Masked-tail
// w=0 adds exact zeros and pair order matches the old 2-unrolled loop -> bitwise-identical.
__global__ void gat_aggCF_kernel(const int* __restrict__ rp, const int* __restrict__ colA,
                                 const float* __restrict__ as8, const float* __restrict__ ad8,
                                 const __hip_bfloat16* __restrict__ h,
                                 const float* __restrict__ bias,
                                 float* __restrict__ outp) {
    int wid = blockIdx.x * 4 + (threadIdx.x >> 6);
    int lane = threadIdx.x & 63;
    int half = lane >> 5;
    unsigned c = (unsigned)(lane & 31);
    int gbase = half << 5;
    int dreal = wid * 2 + half;
    bool valid = dreal < NN;
    int d = valid ? dreal : (NN - 1);
    float adh = ad8[(size_t)d * 8];
    int s0 = rp[d], s1 = rp[d + 1];
    int s1m1 = s1 - 1;
    float acc = 0.f, den = 0.f;

#define ISSUEF(P, SA, SB, AA, AB, VA, VB) do {                         \
        SA = (unsigned)__shfl(myIdx, gbase | ((P) * 2));               \
        SB = (unsigned)__shfl(myIdx, gbase | ((P) * 2 + 1));           \
        AA = as8[SA * 8u]; AB = as8[SB * 8u];                          \
        VA = bf2f(h[SA * 32u + c]); VB = bf2f(h[SB * 32u + c]);        \
    } while (0)

#define CONSF(E0, AA, AB, VA, VB) do {                                 \
        float eA_ = AA + adh, eB_ = AB + adh;                          \
        eA_ = (eA_ > 0.f) ? eA_ : 0.2f * eA_;                          \
        eB_ = (eB_ > 0.f) ? eB_ : 0.2f * eB_;                          \
        float wA_ = __expf(eA_), wB_ = __expf(eB_);                    \
        wA_ = ((E0) < s1) ? wA_ : 0.f;                                 \
        wB_ = ((E0) + 1 < s1) ? wB_ : 0.f;                             \
        den += wA_ + wB_;                                              \
        acc += wA_ * VA + wB_ * VB;                                    \
    } while (0)

    for (int base = s0; base < s1; base += 32) {
        int myIdx = colA[(unsigned)min(base + (int)c, s1m1)];   // lane c: edge base+c index
        int cnt = min(s1 - base, 32);
        int npair = (cnt + 1) >> 1;                             // >=1
        unsigned sA0, sB0, sA1, sB1;
        float aA0, aB0, aA1, aB1, vA0, vB0, vA1, vB1;
        int p = 0, e = base;
        ISSUEF(0, sA0, sB0, aA0, aB0, vA0, vB0);
        int rem = npair - 1;
        while (rem >= 2) {
            ISSUEF(p + 1, sA1, sB1, aA1, aB1, vA1, vB1);
            CONSF(e, aA0, aB0, vA0, vB0); e += 2;
            ISSUEF(p + 2, sA0, sB0, aA0, aB0, vA0, vB0);
            CONSF(e, aA1, aB1, vA1, vB1); e += 2;
            p += 2; rem -= 2;
        }
        if (rem == 1) {
            ISSUEF(p + 1, sA1, sB1, aA1, aB1, vA1, vB1);
            CONSF(e, aA0, aB0, vA0, vB0); e += 2;
            CONSF(e, aA1, aB1, vA1, vB1);
        } else {
            CONSF(e, aA0, aB0, vA0, vB0);
        }
    }
#undef ISSUEF
#undef CONSF

    float o = acc / (den + 1e-16f) + bias[c];
    float t = o;
#pragma unroll
    for (int off = 16; off > 0; off >>= 1) t = fmaxf(t, __shfl_xor(t, off));
    float ex = __expf(o - t);
#pragma unroll
    for (int off = 16; off > 0; off >>= 1) ex += __shfl_xor(ex, off);
    float res = o - t - __logf(ex);
    if (valid) outp[(size_t)d * 32 + c] = res;
}

// ---------------------------------------------------------------- launch
extern "C" void kernel_launch(void* const* d_in, const int* in_sizes, int n_in,
                              void* d_out, int out_size, void* d_ws, size_t ws_size,
                              hipStream_t stream) {
    const float* x   = (const float*)d_in[0];
    const int*   ei  = (const int*)d_in[1];
    const float* W1  = (const float*)d_in[2];
    const float* a1s = (const float*)d_in[3];
    const float* a1d = (const float*)d_in[4];
    const float* b1  = (const float*)d_in[5];
    const float* W2  = (const float*)d_in[6];
    const float* a2s = (const float*)d_in[7];
    const float* a2d = (const float*)d_in[8];
    const float* b2  = (const float*)d_in[9];
    const float* W3  = (const float*)d_in[10];
    const float* a3s = (const float*)d_in[11];
    const float* a3d = (const float*)d_in[12];
    const float* b3  = (const float*)d_in[13];
    float* out = (float*)d_out;

    // workspace layout (~105 MB)
    char* w = (char*)d_ws;
    unsigned char* hbuf8 = (unsigned char*)w;                  // NP*448 fp8 (22.5 MB); layer-3 reuses as bf16 NP*32
    __hip_bfloat16* hbuf3 = (__hip_bfloat16*)w;
    ushort* xb = (ushort*)(w + (size_t)NP * 448);              // NP*256 bf16 (25.7 MB)
    __hip_bfloat16* act = (__hip_bfloat16*)(xb + (size_t)NP * 256);  // NP*448 bf16 (44.9 MB)
    float* as8 = (float*)(act + (size_t)NP * 448);             // N*8 f32
    float* ad8 = as8 + (size_t)NN * 8;                         // N*8 f32
    int* cnt     = (int*)(ad8 + (size_t)NN * 8);               // N
    int* fillc   = cnt + NN;                                   // N
    int* row_ptr = fillc + NN;                                 // N+4 (padded)
    int* tmp     = row_ptr + (NN + 4);                         // N
    int* part    = tmp + NN;                                   // 256
    int* colA    = part + 256;                                 // ET
    char* pw = (char*)(colA + ET);
    pw = (char*)(((uintptr_t)pw + 15) & ~(uintptr_t)15);
    ushort* Wt1 = (ushort*)pw;                                 // 448*256
    ushort* Wt2 = Wt1 + 448 * 256;                             // 448*448
    ushort* Wt3 = Wt2 + 448 * 448;                             // 64*448 (rows 32..63 poison, never staged now)

    hipMemsetAsync(cnt, 0, 2 * (size_t)NN * sizeof(int), stream);  // cnt + fillc

    // fused prep (wt x3 + x->bf16) + CSR count
    gat_prepcnt_kernel<<<PBLK + CBLK, 256, 0, stream>>>(W1, W2, W3, x, Wt1, Wt2, Wt3, xb, ei, cnt);
    gat_scan1_kernel<<<NB_SCAN, 256, 0, stream>>>(cnt, tmp, part);
    gat_scan2_kernel<<<1, 256, 0, stream>>>(part);
    gat_scan3_kernel<<<NB_SCAN, 256, 0, stream>>>(tmp, part, row_ptr);
    gat_fill_kernel<<<CBLK, 256, 0, stream>>>(ei, row_ptr, fillc, colA);

    dim3 gemmBlk(256);
    // XCD-aware head-fused grid for DOA=1 GEMMs: 8 xcd-slots x ceil(196/8) groups x 7 heads
    int swzBlocks = 8 * ((196 + 7) / 8) * 7;   // 1400 (blocks with mt>=196 exit early)
    int mtiles1 = NP / 64;              // 784 (RF=1, layer 3)
    int aggBlocks = (NN + 3) / 4;       // 12500

    // --- layer 1 (alpha fused; h written as fp8)
    gat_gemm_kernel<4, 1, 1, 4><<<swzBlocks, gemmBlk, 0, stream>>>(
        xb, Wt1, hbuf8, a1s, a1d, as8, ad8, NN, 256, 448);
    gat_aggC7_kernel<<<aggBlocks, 256, 0, stream>>>(row_ptr, colA, as8, ad8, hbuf8, b1, act);

    // --- layer 2
    gat_gemm_kernel<4, 1, 1, 4><<<swzBlocks, gemmBlk, 0, stream>>>(
        (const ushort*)act, Wt2, hbuf8, a2s, a2d, as8, ad8, NN, 448, 448);
    gat_aggC7_kernel<<<aggBlocks, 256, 0, stream>>>(row_ptr, colA, as8, ad8, hbuf8, b2, act);

    // --- layer 3 (1 head, 32 ch, NG=2: no poison-B MFMAs/staging, alpha fused, bf16 h)
    gat_gemm_kernel<1, 2, 0, 2><<<dim3(mtiles1, 1), gemmBlk, 0, stream>>>(
        (const ushort*)act, Wt3, hbuf3, a3s, a3d, as8, ad8, NN, 448, 32);
    int fBlocks = (NN + 7) / 8;  // 8 dsts per block (2 per wave)
    gat_aggCF_kernel<<<fBlocks, 256, 0, stream>>>(row_ptr, colA, as8, ad8, hbuf3, b3, out);
}